// Round 1
// baseline (451.746 us; speedup 1.0000x reference)
//
#include <hip/hip_runtime.h>

typedef unsigned short u16;
typedef short short8 __attribute__((ext_vector_type(8)));
typedef float floatx4 __attribute__((ext_vector_type(4)));

#define MFMA16(a, b, c) __builtin_amdgcn_mfma_f32_16x16x32_bf16((a), (b), (c), 0, 0, 0)

__device__ __forceinline__ u16 f2bf(float f) {
  unsigned u = __builtin_bit_cast(unsigned, f);
  u = (u + 0x7fffu + ((u >> 16) & 1u)) >> 16;
  return (u16)u;
}

__device__ __forceinline__ void gload16(const void* g, void* l) {
  typedef __attribute__((address_space(1))) const void GV;
  typedef __attribute__((address_space(3))) void LV;
  __builtin_amdgcn_global_load_lds((GV*)g, (LV*)l, 16, 0, 0);
}

// ---------------- convert / prep kernels ----------------

__global__ void cvt_x_kernel(const float* __restrict__ x, u16* __restrict__ xb, int n4) {
  int i = blockIdx.x * 256 + threadIdx.x;
  if (i >= n4) return;
  float4 v = ((const float4*)x)[i];
  u16 r0 = f2bf(v.x), r1 = f2bf(v.y), r2 = f2bf(v.z), r3 = f2bf(v.w);
  ushort4 r; r.x = r0; r.y = r1; r.z = r2; r.w = r3;
  ((ushort4*)xb)[i] = r;
}

// out[n][k] = bf16(in[k][n]), in is [768][768] f32 row-major
__global__ void cvt_wT_kernel(const float* __restrict__ in, u16* __restrict__ out) {
  __shared__ float tile[64][65];
  const int k0 = blockIdx.x * 64, n0 = blockIdx.y * 64;
  const int t = threadIdx.x;
  const int tr = t >> 6, tc = t & 63;
#pragma unroll
  for (int i = 0; i < 16; ++i) {
    int row = i * 4 + tr;
    tile[row][tc] = in[(size_t)(k0 + row) * 768 + n0 + tc];
  }
  __syncthreads();
#pragma unroll
  for (int i = 0; i < 16; ++i) {
    int row = i * 4 + tr;
    out[(size_t)(n0 + row) * 768 + k0 + tc] = f2bf(tile[tc][row]);
  }
}

__global__ void bias_kernel(const float* __restrict__ table, float* __restrict__ bias) {
  int i = blockIdx.x * 256 + threadIdx.x;
  if (i >= 577 * 577) return;
  int qq = i / 577, kk = i - (i / 577) * 577;
  int idx;
  if (qq == 0 && kk == 0) idx = 9;
  else if (qq == 0) idx = 10;
  else if (kk == 0) idx = 11;
  else {
    int qy = (qq - 1) / 24, qx = (qq - 1) % 24;
    int ky = (kk - 1) / 24, kx = (kk - 1) % 24;
    int ry = qy - ky; ry = ry < -1 ? -1 : (ry > 1 ? 1 : ry);
    int rx = qx - kx; rx = rx < -1 ? -1 : (rx > 1 ? 1 : rx);
    idx = (ry + 1) * 3 + (rx + 1);
  }
  bias[i] = table[idx];
}

// ---------------- GEMM (128x128 tile, BK=32, 2-phase dbuf, global_load_lds) ----------------
// A: [M][768] bf16 row-major. BT: [N][768] bf16 (i.e. B transposed).
// MODE 0: QKV epilogue (scatter q,k,vT).  MODE 1: out = val + bvec[n] (f32).

template <int MODE>
__global__ __launch_bounds__(256) void gemm_kernel(
    const u16* __restrict__ A, const u16* __restrict__ BT,
    const int M, const int NBN,
    float* __restrict__ outF, const float* __restrict__ bvec,
    u16* __restrict__ qarr, u16* __restrict__ karr, u16* __restrict__ vTa) {
  constexpr int K = 768;
  __shared__ u16 As[2][128 * 32];
  __shared__ u16 Bs[2][128 * 32];

  const int bid = blockIdx.x;
  const int nb = bid % NBN, mb = bid / NBN;
  const int tid = threadIdx.x;
  const int w = tid >> 6, l = tid & 63;
  const int wr = w >> 1, wc = w & 1;
  const int l15 = l & 15, l4 = l >> 4;
  const int m0 = mb * 128, n0 = nb * 128;

  floatx4 acc[4][4];
#pragma unroll
  for (int i = 0; i < 4; ++i)
#pragma unroll
    for (int j = 0; j < 4; ++j) acc[i][j] = 0.f;

  const int trow = tid >> 2;     // 0..63
  const int tk = (tid & 3) * 8;  // k element offset

  auto stage = [&](int buf, int kt) {
    const int k0 = kt * 32;
#pragma unroll
    for (int i = 0; i < 2; ++i) {
      int row = i * 64 + trow;
      int ar = m0 + row; if (ar >= M) ar = M - 1;
      gload16(A + (size_t)ar * K + k0 + tk, &As[buf][row * 32 + tk]);
      int br = n0 + row;
      gload16(BT + (size_t)br * K + k0 + tk, &Bs[buf][row * 32 + tk]);
    }
  };

  stage(0, 0);
  __syncthreads();
  int cur = 0;
  for (int kt = 0; kt < 24; ++kt) {
    if (kt + 1 < 24) stage(cur ^ 1, kt + 1);
    short8 af[4], bf[4];
#pragma unroll
    for (int mi = 0; mi < 4; ++mi)
      af[mi] = *(const short8*)&As[cur][(wr * 64 + mi * 16 + l15) * 32 + l4 * 8];
#pragma unroll
    for (int ni = 0; ni < 4; ++ni)
      bf[ni] = *(const short8*)&Bs[cur][(wc * 64 + ni * 16 + l15) * 32 + l4 * 8];
#pragma unroll
    for (int mi = 0; mi < 4; ++mi)
#pragma unroll
      for (int ni = 0; ni < 4; ++ni)
        acc[mi][ni] = MFMA16(af[mi], bf[ni], acc[mi][ni]);
    __syncthreads();
    cur ^= 1;
  }

#pragma unroll
  for (int mi = 0; mi < 4; ++mi) {
#pragma unroll
    for (int i = 0; i < 4; ++i) {
      const int mrow = m0 + wr * 64 + mi * 16 + l4 * 4 + i;
      if (mrow >= M) continue;
      if constexpr (MODE == 0) {
        const int bq = mrow / 577;
        const int sq = mrow - bq * 577;
#pragma unroll
        for (int ni = 0; ni < 4; ++ni) {
          const int ncol = n0 + wc * 64 + ni * 16 + l15;
          const float val = acc[mi][ni][i];
          const int proj = ncol / 768;
          const int nn = ncol - proj * 768;
          const int h = nn >> 6, d = nn & 63;
          const size_t bh = (size_t)bq * 12 + h;
          if (proj == 0)      qarr[(bh * 577 + sq) * 64 + d] = f2bf(val * 0.125f);
          else if (proj == 1) karr[(bh * 577 + sq) * 64 + d] = f2bf(val);
          else                vTa[(bh * 64 + d) * 608 + sq] = f2bf(val);
        }
      } else {
#pragma unroll
        for (int ni = 0; ni < 4; ++ni) {
          const int ncol = n0 + wc * 64 + ni * 16 + l15;
          outF[(size_t)mrow * 768 + ncol] = acc[mi][ni][i] + bvec[ncol];
        }
      }
    }
  }
}

// ---------------- fused flash attention ----------------
// q,k: [384][577][64] bf16 (q pre-scaled by 0.125); vT: [384][64][608] bf16 (pad zeroed)
// bias: [577][577] f32; xa out: [32][577][768] bf16

__global__ __launch_bounds__(256) void attn_kernel(
    const u16* __restrict__ qg, const u16* __restrict__ kg,
    const u16* __restrict__ vT, const float* __restrict__ bias,
    u16* __restrict__ xa) {
  const int bid = blockIdx.x;
  const int bh = bid / 10, qblk = bid % 10;
  const int tid = threadIdx.x;
  const int w = tid >> 6, l = tid & 63;
  const int l15 = l & 15, l4 = l >> 4;
  const int qbase = qblk * 64 + w * 16;

  const u16* qh = qg + (size_t)bh * 577 * 64;
  const u16* kh = kg + (size_t)bh * 577 * 64;
  const u16* vh = vT + (size_t)bh * 64 * 608;

  int qr = qbase + l15; if (qr > 576) qr = 576;
  const short8 qa0 = *(const short8*)(qh + qr * 64 + l4 * 8);
  const short8 qa1 = *(const short8*)(qh + qr * 64 + 32 + l4 * 8);

  floatx4 o[4];
  float m[4], lsum[4];
#pragma unroll
  for (int i = 0; i < 4; ++i) { o[i] = 0.f; m[i] = -1e30f; lsum[i] = 0.f; }

  __shared__ u16 pbuf[4][16][40];

  int bq[4];
#pragma unroll
  for (int i = 0; i < 4; ++i) { int g = qbase + l4 * 4 + i; bq[i] = g > 576 ? 576 : g; }

  for (int t = 0; t < 19; ++t) {
    const int kvb = t * 32;
    int kr0 = kvb + l15;      if (kr0 > 576) kr0 = 576;
    int kr1 = kvb + 16 + l15; if (kr1 > 576) kr1 = 576;
    const short8 kb00 = *(const short8*)(kh + kr0 * 64 + l4 * 8);
    const short8 kb01 = *(const short8*)(kh + kr0 * 64 + 32 + l4 * 8);
    const short8 kb10 = *(const short8*)(kh + kr1 * 64 + l4 * 8);
    const short8 kb11 = *(const short8*)(kh + kr1 * 64 + 32 + l4 * 8);

    floatx4 s0 = 0.f, s1 = 0.f;
    s0 = MFMA16(qa0, kb00, s0);
    s0 = MFMA16(qa1, kb01, s0);
    s1 = MFMA16(qa0, kb10, s1);
    s1 = MFMA16(qa1, kb11, s1);

    const int c0 = kvb + l15, c1 = kvb + 16 + l15;
    const int c0c = c0 > 576 ? 576 : c0, c1c = c1 > 576 ? 576 : c1;
    float p0[4], p1[4];
#pragma unroll
    for (int i = 0; i < 4; ++i) {
      float v0 = s0[i] + bias[bq[i] * 577 + c0c];
      float v1 = s1[i] + bias[bq[i] * 577 + c1c];
      if (c0 > 576) v0 = -1e30f;
      if (c1 > 576) v1 = -1e30f;
      float vm = fmaxf(v0, v1);
      vm = fmaxf(vm, __shfl_xor(vm, 1));
      vm = fmaxf(vm, __shfl_xor(vm, 2));
      vm = fmaxf(vm, __shfl_xor(vm, 4));
      vm = fmaxf(vm, __shfl_xor(vm, 8));
      const float mn = fmaxf(m[i], vm);
      const float sc = __expf(m[i] - mn);
      const float e0 = __expf(v0 - mn);
      const float e1 = __expf(v1 - mn);
      float rs = e0 + e1;
      rs += __shfl_xor(rs, 1);
      rs += __shfl_xor(rs, 2);
      rs += __shfl_xor(rs, 4);
      rs += __shfl_xor(rs, 8);
      lsum[i] = lsum[i] * sc + rs;
      m[i] = mn;
#pragma unroll
      for (int d = 0; d < 4; ++d) o[d][i] *= sc;
      p0[i] = e0; p1[i] = e1;
    }

#pragma unroll
    for (int i = 0; i < 4; ++i) {
      pbuf[w][l4 * 4 + i][l15] = f2bf(p0[i]);
      pbuf[w][l4 * 4 + i][l15 + 16] = f2bf(p1[i]);
    }
    // same-wave LDS RAW with a cross-lane dependency the compiler cannot see:
    // fence all memory ops and drain DS queue before the fragment read.
    asm volatile("s_waitcnt lgkmcnt(0)" ::: "memory");
    const short8 pf = *(const short8*)&pbuf[w][l15][l4 * 8];

#pragma unroll
    for (int d = 0; d < 4; ++d) {
      const short8 vf = *(const short8*)(vh + (d * 16 + l15) * 608 + kvb + l4 * 8);
      o[d] = MFMA16(pf, vf, o[d]);
    }
  }

  const int b = bh / 12, h = bh - (bh / 12) * 12;
#pragma unroll
  for (int i = 0; i < 4; ++i) {
    const int gq = qbase + l4 * 4 + i;
    if (gq < 577) {
      const float inv = 1.f / lsum[i];
      const size_t base = ((size_t)(b * 577 + gq)) * 768 + h * 64 + l15;
#pragma unroll
      for (int d = 0; d < 4; ++d) xa[base + d * 16] = f2bf(o[d][i] * inv);
    }
  }
}

// ---------------- launch ----------------

extern "C" void kernel_launch(void* const* d_in, const int* in_sizes, int n_in,
                              void* d_out, int out_size, void* d_ws, size_t ws_size,
                              hipStream_t stream) {
  const float* x  = (const float*)d_in[0];
  const float* Wq = (const float*)d_in[1];
  const float* Wk = (const float*)d_in[2];
  const float* Wv = (const float*)d_in[3];
  const float* Wo = (const float*)d_in[4];
  const float* bo = (const float*)d_in[5];
  const float* bt = (const float*)d_in[6];
  float* out = (float*)d_out;

  char* ws = (char*)d_ws;
  size_t off = 0;
  auto alloc = [&](size_t bytes) {
    void* p = ws + off;
    off += (bytes + 255) & ~(size_t)255;
    return p;
  };
  u16* xb   = (u16*)alloc((size_t)18464 * 768 * 2);   // also reused as xa after GEMM1
  u16* WT   = (u16*)alloc((size_t)2304 * 768 * 2);
  u16* WoT  = (u16*)alloc((size_t)768 * 768 * 2);
  u16* qa   = (u16*)alloc((size_t)384 * 577 * 64 * 2);
  u16* ka   = (u16*)alloc((size_t)384 * 577 * 64 * 2);
  u16* vT   = (u16*)alloc((size_t)384 * 64 * 608 * 2);
  float* bias = (float*)alloc((size_t)577 * 577 * 4);
  (void)ws_size; (void)in_sizes; (void)n_in; (void)out_size;

  hipMemsetAsync(vT, 0, (size_t)384 * 64 * 608 * 2, stream);

  cvt_x_kernel<<<(18464 * 768 / 4 + 255) / 256, 256, 0, stream>>>(x, xb, 18464 * 768 / 4);
  dim3 tg(12, 12);
  cvt_wT_kernel<<<tg, 256, 0, stream>>>(Wq, WT);
  cvt_wT_kernel<<<tg, 256, 0, stream>>>(Wk, WT + (size_t)768 * 768);
  cvt_wT_kernel<<<tg, 256, 0, stream>>>(Wv, WT + (size_t)2 * 768 * 768);
  cvt_wT_kernel<<<tg, 256, 0, stream>>>(Wo, WoT);
  bias_kernel<<<(577 * 577 + 255) / 256, 256, 0, stream>>>(bt, bias);

  // QKV projection: [18464][768] x [768][2304] -> q,k,vT
  gemm_kernel<0><<<145 * 18, 256, 0, stream>>>(xb, WT, 18464, 18,
                                               nullptr, nullptr, qa, ka, vT);
  // attention -> xa (reuse xb region)
  attn_kernel<<<3840, 256, 0, stream>>>(qa, ka, vT, bias, xb);
  // output projection: xa x WoT + bo -> out (f32)
  gemm_kernel<1><<<145 * 6, 256, 0, stream>>>(xb, WoT, 18464, 6,
                                              out, bo, nullptr, nullptr, nullptr);
}

// Round 2
// 377.779 us; speedup vs baseline: 1.1958x; 1.1958x over previous
//
#include <hip/hip_runtime.h>

typedef unsigned short u16;
typedef short short8 __attribute__((ext_vector_type(8)));
typedef float floatx4 __attribute__((ext_vector_type(4)));

#define MFMA16(a, b, c) __builtin_amdgcn_mfma_f32_16x16x32_bf16((a), (b), (c), 0, 0, 0)

__device__ __forceinline__ u16 f2bf(float f) {
  unsigned u = __builtin_bit_cast(unsigned, f);
  u = (u + 0x7fffu + ((u >> 16) & 1u)) >> 16;
  return (u16)u;
}

__device__ __forceinline__ float exp2hw(float x) {
  float r; asm("v_exp_f32 %0, %1" : "=v"(r) : "v"(x)); return r;
}

__device__ __forceinline__ void gload16(const void* g, void* l) {
  typedef __attribute__((address_space(1))) const void GV;
  typedef __attribute__((address_space(3))) void LV;
  __builtin_amdgcn_global_load_lds((GV*)g, (LV*)l, 16, 0, 0);
}

// ---------------- convert / prep kernels ----------------

__global__ void cvt_x_kernel(const float* __restrict__ x, u16* __restrict__ xb, int n4) {
  int i = blockIdx.x * 256 + threadIdx.x;
  if (i >= n4) return;
  float4 v = ((const float4*)x)[i];
  ushort4 r; r.x = f2bf(v.x); r.y = f2bf(v.y); r.z = f2bf(v.z); r.w = f2bf(v.w);
  ((ushort4*)xb)[i] = r;
}

// out[n][k] = bf16(in[k][n]), in is [768][768] f32 row-major
__global__ void cvt_wT_kernel(const float* __restrict__ in, u16* __restrict__ out) {
  __shared__ float tile[64][65];
  const int k0 = blockIdx.x * 64, n0 = blockIdx.y * 64;
  const int t = threadIdx.x;
  const int tr = t >> 6, tc = t & 63;
#pragma unroll
  for (int i = 0; i < 16; ++i) {
    int row = i * 4 + tr;
    tile[row][tc] = in[(size_t)(k0 + row) * 768 + n0 + tc];
  }
  __syncthreads();
#pragma unroll
  for (int i = 0; i < 16; ++i) {
    int row = i * 4 + tr;
    out[(size_t)(n0 + row) * 768 + k0 + tc] = f2bf(tile[tc][row]);
  }
}

// bias padded to stride 592, pre-scaled by log2(e) for exp2-domain softmax
__global__ void bias_kernel(const float* __restrict__ table, float* __restrict__ bias) {
  int i = blockIdx.x * 256 + threadIdx.x;
  if (i >= 577 * 577) return;
  int qq = i / 577, kk = i - (i / 577) * 577;
  int idx;
  if (qq == 0 && kk == 0) idx = 9;
  else if (qq == 0) idx = 10;
  else if (kk == 0) idx = 11;
  else {
    int qy = (qq - 1) / 24, qx = (qq - 1) % 24;
    int ky = (kk - 1) / 24, kx = (kk - 1) % 24;
    int ry = qy - ky; ry = ry < -1 ? -1 : (ry > 1 ? 1 : ry);
    int rx = qx - kx; rx = rx < -1 ? -1 : (rx > 1 ? 1 : rx);
    idx = (ry + 1) * 3 + (rx + 1);
  }
  bias[qq * 592 + kk] = table[idx] * 1.4426950408889634f;
}

// ---------------- GEMM (128x128 tile, BK=32, 2-phase dbuf, global_load_lds) ----------------

template <int MODE>
__global__ __launch_bounds__(256) void gemm_kernel(
    const u16* __restrict__ A, const u16* __restrict__ BT,
    const int M, const int NBN,
    float* __restrict__ outF, const float* __restrict__ bvec,
    u16* __restrict__ qarr, u16* __restrict__ karr, u16* __restrict__ vTa) {
  constexpr int K = 768;
  __shared__ u16 As[2][128 * 32];
  __shared__ u16 Bs[2][128 * 32];

  const int bid = blockIdx.x;
  const int nb = bid % NBN, mb = bid / NBN;
  const int tid = threadIdx.x;
  const int w = tid >> 6, l = tid & 63;
  const int wr = w >> 1, wc = w & 1;
  const int l15 = l & 15, l4 = l >> 4;
  const int m0 = mb * 128, n0 = nb * 128;

  floatx4 acc[4][4];
#pragma unroll
  for (int i = 0; i < 4; ++i)
#pragma unroll
    for (int j = 0; j < 4; ++j) acc[i][j] = 0.f;

  const int trow = tid >> 2;
  const int tk = (tid & 3) * 8;

  auto stage = [&](int buf, int kt) {
    const int k0 = kt * 32;
#pragma unroll
    for (int i = 0; i < 2; ++i) {
      int row = i * 64 + trow;
      int ar = m0 + row; if (ar >= M) ar = M - 1;
      gload16(A + (size_t)ar * K + k0 + tk, &As[buf][row * 32 + tk]);
      int br = n0 + row;
      gload16(BT + (size_t)br * K + k0 + tk, &Bs[buf][row * 32 + tk]);
    }
  };

  stage(0, 0);
  __syncthreads();
  int cur = 0;
  for (int kt = 0; kt < 24; ++kt) {
    if (kt + 1 < 24) stage(cur ^ 1, kt + 1);
    short8 af[4], bf[4];
#pragma unroll
    for (int mi = 0; mi < 4; ++mi)
      af[mi] = *(const short8*)&As[cur][(wr * 64 + mi * 16 + l15) * 32 + l4 * 8];
#pragma unroll
    for (int ni = 0; ni < 4; ++ni)
      bf[ni] = *(const short8*)&Bs[cur][(wc * 64 + ni * 16 + l15) * 32 + l4 * 8];
#pragma unroll
    for (int mi = 0; mi < 4; ++mi)
#pragma unroll
      for (int ni = 0; ni < 4; ++ni)
        acc[mi][ni] = MFMA16(af[mi], bf[ni], acc[mi][ni]);
    __syncthreads();
    cur ^= 1;
  }

#pragma unroll
  for (int mi = 0; mi < 4; ++mi) {
#pragma unroll
    for (int i = 0; i < 4; ++i) {
      const int mrow = m0 + wr * 64 + mi * 16 + l4 * 4 + i;
      if (mrow >= M) continue;
      if constexpr (MODE == 0) {
        const int bq = mrow / 577;
        const int sq = mrow - bq * 577;
#pragma unroll
        for (int ni = 0; ni < 4; ++ni) {
          const int ncol = n0 + wc * 64 + ni * 16 + l15;
          const float val = acc[mi][ni][i];
          const int proj = ncol / 768;
          const int nn = ncol - proj * 768;
          const int h = nn >> 6, d = nn & 63;
          const size_t bh = (size_t)bq * 12 + h;
          // q pre-scaled by 0.125 * log2(e) -> softmax runs in exp2 domain
          if (proj == 0)      qarr[(bh * 577 + sq) * 64 + d] = f2bf(val * 0.18033688011112042f);
          else if (proj == 1) karr[(bh * 577 + sq) * 64 + d] = f2bf(val);
          else                vTa[(bh * 64 + d) * 608 + sq] = f2bf(val);
        }
      } else {
#pragma unroll
        for (int ni = 0; ni < 4; ++ni) {
          const int ncol = n0 + wc * 64 + ni * 16 + l15;
          outF[(size_t)mrow * 768 + ncol] = acc[mi][ni][i] + bvec[ncol];
        }
      }
    }
  }
}

// ---------------- fused flash attention (swapped QK^T, sigma-permuted K rows) ----------------
// Lane (l4,l15) ends up holding P[q = qbase+g*16+l15][k = kvb + l4*8 + j], j=0..7 —
// exactly the PV B-fragment. No LDS bounce, no P shuffles.

__global__ __launch_bounds__(256, 4) void attn_kernel(
    const u16* __restrict__ qg, const u16* __restrict__ kg,
    const u16* __restrict__ vT, const float* __restrict__ bias,
    u16* __restrict__ xa) {
  const int bid = blockIdx.x;
  const int bh = bid / 5, qblk = bid % 5;
  const int tid = threadIdx.x;
  const int w = tid >> 6, l = tid & 63;
  const int l15 = l & 15, l4 = l >> 4;
  const int qbase = qblk * 128 + w * 32;

  const u16* qh = qg + (size_t)bh * 577 * 64;
  const u16* kh = kg + (size_t)bh * 577 * 64;
  const u16* vh = vT + (size_t)bh * 64 * 608;

  short8 qf[2][2];
  int bq[2];
#pragma unroll
  for (int g = 0; g < 2; ++g) {
    int qr = qbase + g * 16 + l15; if (qr > 576) qr = 576;
    bq[g] = qr;
    qf[g][0] = *(const short8*)(qh + qr * 64 + l4 * 8);
    qf[g][1] = *(const short8*)(qh + qr * 64 + 32 + l4 * 8);
  }

  floatx4 o[2][4];
  float m[2] = {-1e30f, -1e30f}, lsum[2] = {0.f, 0.f};
#pragma unroll
  for (int g = 0; g < 2; ++g)
#pragma unroll
    for (int d = 0; d < 4; ++d) o[g][d] = 0.f;

  const int sig = (l15 >> 2) * 8 + (l15 & 3);  // sigma0: output row r holds K-row l4*8+i

  for (int t = 0; t < 19; ++t) {
    const int kvb = t * 32;
    int r0 = kvb + sig;     if (r0 > 576) r0 = 576;
    int r1 = kvb + sig + 4; if (r1 > 576) r1 = 576;
    const short8 k0lo = *(const short8*)(kh + r0 * 64 + l4 * 8);
    const short8 k0hi = *(const short8*)(kh + r0 * 64 + 32 + l4 * 8);
    const short8 k1lo = *(const short8*)(kh + r1 * 64 + l4 * 8);
    const short8 k1hi = *(const short8*)(kh + r1 * 64 + 32 + l4 * 8);

    float v[2][8];
#pragma unroll
    for (int g = 0; g < 2; ++g) {
      floatx4 s0 = 0.f, s1 = 0.f;
      s0 = MFMA16(k0lo, qf[g][0], s0);
      s0 = MFMA16(k0hi, qf[g][1], s0);
      s1 = MFMA16(k1lo, qf[g][0], s1);
      s1 = MFMA16(k1hi, qf[g][1], s1);
      const float* bp = bias + bq[g] * 592 + kvb + l4 * 8;
      const float4 b0 = *(const float4*)bp;
      const float4 b1 = *(const float4*)(bp + 4);
      v[g][0] = s0[0] + b0.x; v[g][1] = s0[1] + b0.y;
      v[g][2] = s0[2] + b0.z; v[g][3] = s0[3] + b0.w;
      v[g][4] = s1[0] + b1.x; v[g][5] = s1[1] + b1.y;
      v[g][6] = s1[2] + b1.z; v[g][7] = s1[3] + b1.w;
    }

    if (t == 18) {
      const int kg0 = kvb + l4 * 8;
#pragma unroll
      for (int j = 0; j < 8; ++j)
        if (kg0 + j > 576) { v[0][j] = -1e30f; v[1][j] = -1e30f; }
    }

    float vm2[2];
#pragma unroll
    for (int g = 0; g < 2; ++g) {
      float vm = v[g][0];
#pragma unroll
      for (int j = 1; j < 8; ++j) vm = fmaxf(vm, v[g][j]);
      vm = fmaxf(vm, __shfl_xor(vm, 16));
      vm = fmaxf(vm, __shfl_xor(vm, 32));
      vm2[g] = vm;
    }

    // T13 defer-max: only rescale when some row's max grew past THR=8 (log2 units)
    if (__any((vm2[0] > m[0] + 8.f) || (vm2[1] > m[1] + 8.f))) {
#pragma unroll
      for (int g = 0; g < 2; ++g) {
        const float mn = fmaxf(m[g], vm2[g]);
        const float sc = exp2hw(m[g] - mn);
        lsum[g] *= sc;
#pragma unroll
        for (int d = 0; d < 4; ++d) o[g][d] *= sc;
        m[g] = mn;
      }
    }

    short8 pf[2];
#pragma unroll
    for (int g = 0; g < 2; ++g) {
      float e[8];
      float rs = 0.f;
#pragma unroll
      for (int j = 0; j < 8; ++j) { e[j] = exp2hw(v[g][j] - m[g]); rs += e[j]; }
      rs += __shfl_xor(rs, 16);
      rs += __shfl_xor(rs, 32);
      lsum[g] += rs;
      short8 p;
#pragma unroll
      for (int j = 0; j < 8; ++j) p[j] = (short)f2bf(e[j]);
      pf[g] = p;
    }

#pragma unroll
    for (int d = 0; d < 4; ++d) {
      const short8 vf = *(const short8*)(vh + (d * 16 + l15) * 608 + kvb + l4 * 8);
      o[0][d] = MFMA16(vf, pf[0], o[0][d]);
      o[1][d] = MFMA16(vf, pf[1], o[1][d]);
    }
  }

  const int b = bh / 12, h = bh - (bh / 12) * 12;
#pragma unroll
  for (int g = 0; g < 2; ++g) {
    const int gq = qbase + g * 16 + l15;
    if (gq < 577) {
      const float inv = 1.f / lsum[g];
      u16* op = xa + ((size_t)(b * 577 + gq)) * 768 + h * 64 + l4 * 4;
#pragma unroll
      for (int d = 0; d < 4; ++d) {
        unsigned w0 = f2bf(o[g][d][0] * inv) | ((unsigned)f2bf(o[g][d][1] * inv) << 16);
        unsigned w1 = f2bf(o[g][d][2] * inv) | ((unsigned)f2bf(o[g][d][3] * inv) << 16);
        *(unsigned*)(op + d * 16) = w0;
        *(unsigned*)(op + d * 16 + 2) = w1;
      }
    }
  }
}

// ---------------- launch ----------------

extern "C" void kernel_launch(void* const* d_in, const int* in_sizes, int n_in,
                              void* d_out, int out_size, void* d_ws, size_t ws_size,
                              hipStream_t stream) {
  const float* x  = (const float*)d_in[0];
  const float* Wq = (const float*)d_in[1];
  const float* Wk = (const float*)d_in[2];
  const float* Wv = (const float*)d_in[3];
  const float* Wo = (const float*)d_in[4];
  const float* bo = (const float*)d_in[5];
  const float* bt = (const float*)d_in[6];
  float* out = (float*)d_out;

  char* ws = (char*)d_ws;
  size_t off = 0;
  auto alloc = [&](size_t bytes) {
    void* p = ws + off;
    off += (bytes + 255) & ~(size_t)255;
    return p;
  };
  u16* xb   = (u16*)alloc((size_t)18464 * 768 * 2);   // reused as xa after GEMM0
  u16* WT   = (u16*)alloc((size_t)2304 * 768 * 2);
  u16* WoT  = (u16*)alloc((size_t)768 * 768 * 2);
  u16* qa   = (u16*)alloc((size_t)384 * 577 * 64 * 2);
  u16* ka   = (u16*)alloc((size_t)384 * 577 * 64 * 2);
  u16* vT   = (u16*)alloc((size_t)384 * 64 * 608 * 2);
  float* bias = (float*)alloc(((size_t)577 * 592 + 256) * 4);  // padded stride + tail slack
  (void)ws_size; (void)in_sizes; (void)n_in; (void)out_size;

  hipMemsetAsync(vT, 0, (size_t)384 * 64 * 608 * 2, stream);

  cvt_x_kernel<<<(18464 * 768 / 4 + 255) / 256, 256, 0, stream>>>(x, xb, 18464 * 768 / 4);
  dim3 tg(12, 12);
  cvt_wT_kernel<<<tg, 256, 0, stream>>>(Wq, WT);
  cvt_wT_kernel<<<tg, 256, 0, stream>>>(Wk, WT + (size_t)768 * 768);
  cvt_wT_kernel<<<tg, 256, 0, stream>>>(Wv, WT + (size_t)2 * 768 * 768);
  cvt_wT_kernel<<<tg, 256, 0, stream>>>(Wo, WoT);
  bias_kernel<<<(577 * 577 + 255) / 256, 256, 0, stream>>>(bt, bias);

  // QKV projection: [18464][768] x [768][2304] -> q,k,vT
  gemm_kernel<0><<<145 * 18, 256, 0, stream>>>(xb, WT, 18464, 18,
                                               nullptr, nullptr, qa, ka, vT);
  // attention -> xa (reuse xb region); 384 bh * 5 qblocks, 4 waves * 32 q-rows
  attn_kernel<<<1920, 256, 0, stream>>>(qa, ka, vT, bias, xb);
  // output projection: xa x WoT + bo -> out (f32)
  gemm_kernel<1><<<145 * 6, 256, 0, stream>>>(xb, WoT, 18464, 6,
                                              out, bo, nullptr, nullptr, nullptr);
}

// Round 4
// 365.953 us; speedup vs baseline: 1.2344x; 1.0323x over previous
//
#include <hip/hip_runtime.h>

typedef unsigned short u16;
typedef short short8 __attribute__((ext_vector_type(8)));
typedef float floatx4 __attribute__((ext_vector_type(4)));

#define MFMA16(a, b, c) __builtin_amdgcn_mfma_f32_16x16x32_bf16((a), (b), (c), 0, 0, 0)

__device__ __forceinline__ u16 f2bf(float f) {
  unsigned u = __builtin_bit_cast(unsigned, f);
  u = (u + 0x7fffu + ((u >> 16) & 1u)) >> 16;
  return (u16)u;
}

__device__ __forceinline__ float exp2hw(float x) {
  float r; asm("v_exp_f32 %0, %1" : "=v"(r) : "v"(x)); return r;
}

// pack two f32 -> one u32 holding 2 bf16 (RNE), single VALU op on gfx950
__device__ __forceinline__ unsigned cvtpk_bf16(float lo, float hi) {
  unsigned r;
  asm("v_cvt_pk_bf16_f32 %0, %1, %2" : "=v"(r) : "v"(lo), "v"(hi));
  return r;
}

__device__ __forceinline__ void gload16(const void* g, void* l) {
  typedef __attribute__((address_space(1))) const void GV;
  typedef __attribute__((address_space(3))) void LV;
  __builtin_amdgcn_global_load_lds((GV*)g, (LV*)l, 16, 0, 0);
}

// ---------------- convert / prep kernels ----------------

__global__ void cvt_x_kernel(const float* __restrict__ x, u16* __restrict__ xb, int n4) {
  int i = blockIdx.x * 256 + threadIdx.x;
  if (i >= n4) return;
  float4 v = ((const float4*)x)[i];
  ushort4 r; r.x = f2bf(v.x); r.y = f2bf(v.y); r.z = f2bf(v.z); r.w = f2bf(v.w);
  ((ushort4*)xb)[i] = r;
}

// out[n][k] = bf16(in[k][n]), in is [768][768] f32 row-major
__global__ void cvt_wT_kernel(const float* __restrict__ in, u16* __restrict__ out) {
  __shared__ float tile[64][65];
  const int k0 = blockIdx.x * 64, n0 = blockIdx.y * 64;
  const int t = threadIdx.x;
  const int tr = t >> 6, tc = t & 63;
#pragma unroll
  for (int i = 0; i < 16; ++i) {
    int row = i * 4 + tr;
    tile[row][tc] = in[(size_t)(k0 + row) * 768 + n0 + tc];
  }
  __syncthreads();
#pragma unroll
  for (int i = 0; i < 16; ++i) {
    int row = i * 4 + tr;
    out[(size_t)(n0 + row) * 768 + k0 + tc] = f2bf(tile[tc][row]);
  }
}

// bias padded to stride 592, pre-scaled by log2(e) for exp2-domain softmax
__global__ void bias_kernel(const float* __restrict__ table, float* __restrict__ bias) {
  int i = blockIdx.x * 256 + threadIdx.x;
  if (i >= 577 * 577) return;
  int qq = i / 577, kk = i - (i / 577) * 577;
  int idx;
  if (qq == 0 && kk == 0) idx = 9;
  else if (qq == 0) idx = 10;
  else if (kk == 0) idx = 11;
  else {
    int qy = (qq - 1) / 24, qx = (qq - 1) % 24;
    int ky = (kk - 1) / 24, kx = (kk - 1) % 24;
    int ry = qy - ky; ry = ry < -1 ? -1 : (ry > 1 ? 1 : ry);
    int rx = qx - kx; rx = rx < -1 ? -1 : (rx > 1 ? 1 : rx);
    idx = (ry + 1) * 3 + (rx + 1);
  }
  bias[qq * 592 + kk] = table[idx] * 1.4426950408889634f;
}

// v [bh][577][64] -> vT [bh][64][608] via LDS tile (pad cols left as memset zeros)
__global__ __launch_bounds__(256) void transp_v(const u16* __restrict__ v, u16* __restrict__ vT) {
  __shared__ u16 tile[64][65];
  const int bh = blockIdx.x / 10, st = blockIdx.x - (blockIdx.x / 10) * 10;
  const int s0 = st * 64;
  const int t = threadIdx.x;
  const int rq = t >> 6, c = t & 63;
  const u16* vsrc = v + (size_t)bh * 577 * 64;
#pragma unroll
  for (int i = 0; i < 16; ++i) {
    int row = i * 4 + rq;
    int s = s0 + row;
    tile[row][c] = (s < 577) ? vsrc[(size_t)s * 64 + c] : (u16)0;
  }
  __syncthreads();
  u16* vdst = vT + (size_t)bh * 64 * 608;
#pragma unroll
  for (int i = 0; i < 16; ++i) {
    int drow = i * 4 + rq;
    int scol = s0 + c;
    if (scol < 577) vdst[(size_t)drow * 608 + scol] = tile[c][drow];
  }
}

// ---------------- GEMM (128x128 tile, BK=32, 2-phase dbuf, global_load_lds) ----------------

template <int MODE>
__global__ __launch_bounds__(256) void gemm_kernel(
    const u16* __restrict__ A, const u16* __restrict__ BT,
    const int M, const int NBN,
    float* __restrict__ outF, const float* __restrict__ bvec,
    u16* __restrict__ qarr, u16* __restrict__ karr, u16* __restrict__ varr) {
  constexpr int K = 768;
  __shared__ u16 As[2][128 * 32];
  __shared__ u16 Bs[2][128 * 32];

  const int bid = blockIdx.x;
  const int nb = bid % NBN, mb = bid / NBN;
  const int tid = threadIdx.x;
  const int w = tid >> 6, l = tid & 63;
  const int wr = w >> 1, wc = w & 1;
  const int l15 = l & 15, l4 = l >> 4;
  const int m0 = mb * 128, n0 = nb * 128;

  floatx4 acc[4][4];
#pragma unroll
  for (int i = 0; i < 4; ++i)
#pragma unroll
    for (int j = 0; j < 4; ++j) acc[i][j] = 0.f;

  const int trow = tid >> 2;
  const int tk = (tid & 3) * 8;

  auto stage = [&](int buf, int kt) {
    const int k0 = kt * 32;
#pragma unroll
    for (int i = 0; i < 2; ++i) {
      int row = i * 64 + trow;
      int ar = m0 + row; if (ar >= M) ar = M - 1;
      gload16(A + (size_t)ar * K + k0 + tk, &As[buf][row * 32 + tk]);
      int br = n0 + row;
      gload16(BT + (size_t)br * K + k0 + tk, &Bs[buf][row * 32 + tk]);
    }
  };

  stage(0, 0);
  __syncthreads();
  int cur = 0;
  for (int kt = 0; kt < 24; ++kt) {
    if (kt + 1 < 24) stage(cur ^ 1, kt + 1);
    short8 af[4], bf[4];
#pragma unroll
    for (int mi = 0; mi < 4; ++mi)
      af[mi] = *(const short8*)&As[cur][(wr * 64 + mi * 16 + l15) * 32 + l4 * 8];
#pragma unroll
    for (int ni = 0; ni < 4; ++ni)
      bf[ni] = *(const short8*)&Bs[cur][(wc * 64 + ni * 16 + l15) * 32 + l4 * 8];
#pragma unroll
    for (int mi = 0; mi < 4; ++mi)
#pragma unroll
      for (int ni = 0; ni < 4; ++ni)
        acc[mi][ni] = MFMA16(af[mi], bf[ni], acc[mi][ni]);
    __syncthreads();
    cur ^= 1;
  }

#pragma unroll
  for (int mi = 0; mi < 4; ++mi) {
#pragma unroll
    for (int i = 0; i < 4; ++i) {
      const int mrow = m0 + wr * 64 + mi * 16 + l4 * 4 + i;
      if (mrow >= M) continue;
      if constexpr (MODE == 0) {
        const int bq = mrow / 577;
        const int sq = mrow - bq * 577;
#pragma unroll
        for (int ni = 0; ni < 4; ++ni) {
          const int ncol = n0 + wc * 64 + ni * 16 + l15;
          const float val = acc[mi][ni][i];
          const int proj = ncol / 768;
          const int nn = ncol - proj * 768;
          const int h = nn >> 6, d = nn & 63;
          const size_t bh = (size_t)bq * 12 + h;
          // q pre-scaled by 0.125 * log2(e) -> softmax runs in exp2 domain
          if (proj == 0)      qarr[(bh * 577 + sq) * 64 + d] = f2bf(val * 0.18033688011112042f);
          else if (proj == 1) karr[(bh * 577 + sq) * 64 + d] = f2bf(val);
          else                varr[(bh * 577 + sq) * 64 + d] = f2bf(val);
        }
      } else {
#pragma unroll
        for (int ni = 0; ni < 4; ++ni) {
          const int ncol = n0 + wc * 64 + ni * 16 + l15;
          outF[(size_t)mrow * 768 + ncol] = acc[mi][ni][i] + bvec[ncol];
        }
      }
    }
  }
}

// ---------------- fused flash attention (swapped QK^T, register-pipelined) ----------------
// Lane (l4,l15) holds P[q = qbase+g*16+l15][k = kvb + l4*8 + j], j=0..7 — exactly the PV
// B-fragment. K-fragments + bias for tile t+1 prefetched into a second named register set.

__global__ __launch_bounds__(256, 2) void attn_kernel(
    const u16* __restrict__ qg, const u16* __restrict__ kg,
    const u16* __restrict__ vT, const float* __restrict__ bias,
    u16* __restrict__ xa) {
  const int bid = blockIdx.x;
  const int bh = bid / 5, qblk = bid % 5;
  const int tid = threadIdx.x;
  const int w = tid >> 6, l = tid & 63;
  const int l15 = l & 15, l4 = l >> 4;
  const int qbase = qblk * 128 + w * 32;

  const u16* qh = qg + (size_t)bh * 577 * 64;
  const u16* kh = kg + (size_t)bh * 577 * 64;
  const u16* vh = vT + (size_t)bh * 64 * 608;

  short8 qf[2][2];
  int bq[2];
#pragma unroll
  for (int g = 0; g < 2; ++g) {
    int qr = qbase + g * 16 + l15; if (qr > 576) qr = 576;
    bq[g] = qr;
    qf[g][0] = *(const short8*)(qh + qr * 64 + l4 * 8);
    qf[g][1] = *(const short8*)(qh + qr * 64 + 32 + l4 * 8);
  }

  floatx4 o[2][4];
  float m[2] = {-1e30f, -1e30f}, lsum[2] = {0.f, 0.f};
#pragma unroll
  for (int g = 0; g < 2; ++g)
#pragma unroll
    for (int d = 0; d < 4; ++d) o[g][d] = 0.f;

  const int sig = (l15 >> 2) * 8 + (l15 & 3);  // sigma0 K-row permutation

  auto LOADK = [&](int t, short8& A0, short8& A1, short8& A2, short8& A3,
                   float4& B0, float4& B1, float4& B2, float4& B3) {
    const int kvb = t * 32;
    int r0 = kvb + sig;     if (r0 > 576) r0 = 576;
    int r1 = kvb + sig + 4; if (r1 > 576) r1 = 576;
    A0 = *(const short8*)(kh + r0 * 64 + l4 * 8);
    A1 = *(const short8*)(kh + r0 * 64 + 32 + l4 * 8);
    A2 = *(const short8*)(kh + r1 * 64 + l4 * 8);
    A3 = *(const short8*)(kh + r1 * 64 + 32 + l4 * 8);
    const float* bp0 = bias + bq[0] * 592 + kvb + l4 * 8;
    B0 = *(const float4*)bp0;
    B1 = *(const float4*)(bp0 + 4);
    const float* bp1 = bias + bq[1] * 592 + kvb + l4 * 8;
    B2 = *(const float4*)bp1;
    B3 = *(const float4*)(bp1 + 4);
  };

  auto COMP = [&](int t, short8 A0, short8 A1, short8 A2, short8 A3,
                  float4 B0, float4 B1, float4 B2, float4 B3, bool tail) {
    const int kvb = t * 32;
    // V loads issued first; consumed after softmax -> latency hidden by QK+softmax
    const u16* vp = vh + l15 * 608 + kvb + l4 * 8;
    const short8 vf0 = *(const short8*)(vp);
    const short8 vf1 = *(const short8*)(vp + (size_t)16 * 608);
    const short8 vf2 = *(const short8*)(vp + (size_t)32 * 608);
    const short8 vf3 = *(const short8*)(vp + (size_t)48 * 608);

    float v0[8], v1[8];
    {
      floatx4 s0 = 0.f, s1 = 0.f, s2 = 0.f, s3 = 0.f;
      __builtin_amdgcn_s_setprio(1);
      s0 = MFMA16(A0, qf[0][0], s0);
      s0 = MFMA16(A1, qf[0][1], s0);
      s1 = MFMA16(A2, qf[0][0], s1);
      s1 = MFMA16(A3, qf[0][1], s1);
      s2 = MFMA16(A0, qf[1][0], s2);
      s2 = MFMA16(A1, qf[1][1], s2);
      s3 = MFMA16(A2, qf[1][0], s3);
      s3 = MFMA16(A3, qf[1][1], s3);
      __builtin_amdgcn_s_setprio(0);
      v0[0] = s0[0] + B0.x; v0[1] = s0[1] + B0.y; v0[2] = s0[2] + B0.z; v0[3] = s0[3] + B0.w;
      v0[4] = s1[0] + B1.x; v0[5] = s1[1] + B1.y; v0[6] = s1[2] + B1.z; v0[7] = s1[3] + B1.w;
      v1[0] = s2[0] + B2.x; v1[1] = s2[1] + B2.y; v1[2] = s2[2] + B2.z; v1[3] = s2[3] + B2.w;
      v1[4] = s3[0] + B3.x; v1[5] = s3[1] + B3.y; v1[6] = s3[2] + B3.z; v1[7] = s3[3] + B3.w;
    }

    if (tail) {
      const int kg0 = kvb + l4 * 8;
#pragma unroll
      for (int j = 0; j < 8; ++j)
        if (kg0 + j > 576) { v0[j] = -1e30f; v1[j] = -1e30f; }
    }

    float vmA = fmaxf(fmaxf(fmaxf(v0[0], v0[1]), fmaxf(v0[2], v0[3])),
                      fmaxf(fmaxf(v0[4], v0[5]), fmaxf(v0[6], v0[7])));
    float vmB = fmaxf(fmaxf(fmaxf(v1[0], v1[1]), fmaxf(v1[2], v1[3])),
                      fmaxf(fmaxf(v1[4], v1[5]), fmaxf(v1[6], v1[7])));
    vmA = fmaxf(vmA, __shfl_xor(vmA, 16)); vmA = fmaxf(vmA, __shfl_xor(vmA, 32));
    vmB = fmaxf(vmB, __shfl_xor(vmB, 16)); vmB = fmaxf(vmB, __shfl_xor(vmB, 32));

    // T13 defer-max: rescale only when some row max grew past THR=8 (log2 units)
    if (__any((vmA > m[0] + 8.f) || (vmB > m[1] + 8.f))) {
      const float mn0 = fmaxf(m[0], vmA), mn1 = fmaxf(m[1], vmB);
      const float sc0 = exp2hw(m[0] - mn0), sc1 = exp2hw(m[1] - mn1);
      lsum[0] *= sc0; lsum[1] *= sc1;
#pragma unroll
      for (int d = 0; d < 4; ++d) { o[0][d] *= sc0; o[1][d] *= sc1; }
      m[0] = mn0; m[1] = mn1;
    }

    float e0[8], e1[8];
    float rs0 = 0.f, rs1 = 0.f;
#pragma unroll
    for (int j = 0; j < 8; ++j) { e0[j] = exp2hw(v0[j] - m[0]); rs0 += e0[j]; }
#pragma unroll
    for (int j = 0; j < 8; ++j) { e1[j] = exp2hw(v1[j] - m[1]); rs1 += e1[j]; }
    rs0 += __shfl_xor(rs0, 16); rs0 += __shfl_xor(rs0, 32);
    rs1 += __shfl_xor(rs1, 16); rs1 += __shfl_xor(rs1, 32);
    lsum[0] += rs0; lsum[1] += rs1;

    union PU { unsigned u[4]; short8 s; };
    PU p0, p1;
#pragma unroll
    for (int j = 0; j < 4; ++j) {
      p0.u[j] = cvtpk_bf16(e0[2 * j], e0[2 * j + 1]);
      p1.u[j] = cvtpk_bf16(e1[2 * j], e1[2 * j + 1]);
    }

    __builtin_amdgcn_s_setprio(1);
    o[0][0] = MFMA16(vf0, p0.s, o[0][0]);
    o[1][0] = MFMA16(vf0, p1.s, o[1][0]);
    o[0][1] = MFMA16(vf1, p0.s, o[0][1]);
    o[1][1] = MFMA16(vf1, p1.s, o[1][1]);
    o[0][2] = MFMA16(vf2, p0.s, o[0][2]);
    o[1][2] = MFMA16(vf2, p1.s, o[1][2]);
    o[0][3] = MFMA16(vf3, p0.s, o[0][3]);
    o[1][3] = MFMA16(vf3, p1.s, o[1][3]);
    __builtin_amdgcn_s_setprio(0);
  };

  short8 a0, a1, a2, a3, b0, b1, b2, b3;
  float4 c0, c1, c2, c3, d0, d1, d2, d3;
  LOADK(0, a0, a1, a2, a3, c0, c1, c2, c3);
  for (int t = 0; t < 18; t += 2) {
    LOADK(t + 1, b0, b1, b2, b3, d0, d1, d2, d3);
    COMP(t, a0, a1, a2, a3, c0, c1, c2, c3, false);
    LOADK(t + 2, a0, a1, a2, a3, c0, c1, c2, c3);
    COMP(t + 1, b0, b1, b2, b3, d0, d1, d2, d3, false);
  }
  COMP(18, a0, a1, a2, a3, c0, c1, c2, c3, true);

  const int b = bh / 12, h = bh - (bh / 12) * 12;
#pragma unroll
  for (int g = 0; g < 2; ++g) {
    const int gq = qbase + g * 16 + l15;
    if (gq < 577) {
      const float inv = 1.f / lsum[g];
      u16* op = xa + ((size_t)(b * 577 + gq)) * 768 + h * 64 + l4 * 4;
#pragma unroll
      for (int d = 0; d < 4; ++d) {
        unsigned w0 = cvtpk_bf16(o[g][d][0] * inv, o[g][d][1] * inv);
        unsigned w1 = cvtpk_bf16(o[g][d][2] * inv, o[g][d][3] * inv);
        *(unsigned*)(op + d * 16) = w0;
        *(unsigned*)(op + d * 16 + 2) = w1;
      }
    }
  }
}

// ---------------- launch ----------------

extern "C" void kernel_launch(void* const* d_in, const int* in_sizes, int n_in,
                              void* d_out, int out_size, void* d_ws, size_t ws_size,
                              hipStream_t stream) {
  const float* x  = (const float*)d_in[0];
  const float* Wq = (const float*)d_in[1];
  const float* Wk = (const float*)d_in[2];
  const float* Wv = (const float*)d_in[3];
  const float* Wo = (const float*)d_in[4];
  const float* bo = (const float*)d_in[5];
  const float* bt = (const float*)d_in[6];
  float* out = (float*)d_out;

  char* ws = (char*)d_ws;
  size_t off = 0;
  auto alloc = [&](size_t bytes) {
    void* p = ws + off;
    off += (bytes + 255) & ~(size_t)255;
    return p;
  };
  u16* xb   = (u16*)alloc((size_t)18464 * 768 * 2);   // reused as xa after GEMM0
  u16* WT   = (u16*)alloc((size_t)2304 * 768 * 2);
  u16* WoT  = (u16*)alloc((size_t)768 * 768 * 2);
  u16* qa   = (u16*)alloc((size_t)384 * 577 * 64 * 2);
  u16* ka   = (u16*)alloc((size_t)384 * 577 * 64 * 2);
  u16* vT   = (u16*)alloc((size_t)384 * 64 * 608 * 2);
  float* bias = (float*)alloc(((size_t)577 * 592 + 256) * 4);
  // V row-major scratch lives in d_out (56.7 MB f32) — fully overwritten by GEMM1 later.
  u16* va   = (u16*)d_out;
  (void)ws_size; (void)in_sizes; (void)n_in; (void)out_size;

  (void)hipMemsetAsync(vT, 0, (size_t)384 * 64 * 608 * 2, stream);

  cvt_x_kernel<<<(18464 * 768 / 4 + 255) / 256, 256, 0, stream>>>(x, xb, 18464 * 768 / 4);
  dim3 tg(12, 12);
  cvt_wT_kernel<<<tg, 256, 0, stream>>>(Wq, WT);
  cvt_wT_kernel<<<tg, 256, 0, stream>>>(Wk, WT + (size_t)768 * 768);
  cvt_wT_kernel<<<tg, 256, 0, stream>>>(Wv, WT + (size_t)2 * 768 * 768);
  cvt_wT_kernel<<<tg, 256, 0, stream>>>(Wo, WoT);
  bias_kernel<<<(577 * 577 + 255) / 256, 256, 0, stream>>>(bt, bias);

  // QKV projection: [18464][768] x [768][2304] -> q,k,v (all row-major, coalesced stores)
  gemm_kernel<0><<<145 * 18, 256, 0, stream>>>(xb, WT, 18464, 18,
                                               nullptr, nullptr, qa, ka, va);
  // v -> vT
  transp_v<<<3840, 256, 0, stream>>>(va, vT);
  // attention -> xa (reuse xb region)
  attn_kernel<<<1920, 256, 0, stream>>>(qa, ka, vT, bias, xb);
  // output projection: xa x WoT + bo -> out (f32)
  gemm_kernel<1><<<145 * 6, 256, 0, stream>>>(xb, WoT, 18464, 6,
                                              out, bo, nullptr, nullptr, nullptr);
}

// Round 5
// 297.688 us; speedup vs baseline: 1.5175x; 1.2293x over previous
//
#include <hip/hip_runtime.h>

typedef unsigned short u16;
typedef short short8 __attribute__((ext_vector_type(8)));
typedef float floatx4 __attribute__((ext_vector_type(4)));

#define MFMA16(a, b, c) __builtin_amdgcn_mfma_f32_16x16x32_bf16((a), (b), (c), 0, 0, 0)

__device__ __forceinline__ u16 f2bf(float f) {
  unsigned u = __builtin_bit_cast(unsigned, f);
  u = (u + 0x7fffu + ((u >> 16) & 1u)) >> 16;
  return (u16)u;
}

__device__ __forceinline__ float exp2hw(float x) {
  float r; asm("v_exp_f32 %0, %1" : "=v"(r) : "v"(x)); return r;
}

__device__ __forceinline__ unsigned cvtpk_bf16(float lo, float hi) {
  unsigned r;
  asm("v_cvt_pk_bf16_f32 %0, %1, %2" : "=v"(r) : "v"(lo), "v"(hi));
  return r;
}

__device__ __forceinline__ float bflo(unsigned u) {
  return __builtin_bit_cast(float, u << 16);
}
__device__ __forceinline__ float bfhi(unsigned u) {
  return __builtin_bit_cast(float, u & 0xffff0000u);
}

__device__ __forceinline__ void gload16(const void* g, void* l) {
  typedef __attribute__((address_space(1))) const void GV;
  typedef __attribute__((address_space(3))) void LV;
  __builtin_amdgcn_global_load_lds((GV*)g, (LV*)l, 16, 0, 0);
}

// ---------------- convert / prep kernels ----------------

__global__ void cvt_x_kernel(const float* __restrict__ x, u16* __restrict__ xb, int n4) {
  int i = blockIdx.x * 256 + threadIdx.x;
  if (i >= n4) return;
  float4 v = ((const float4*)x)[i];
  ushort4 r; r.x = f2bf(v.x); r.y = f2bf(v.y); r.z = f2bf(v.z); r.w = f2bf(v.w);
  ((ushort4*)xb)[i] = r;
}

// out[n][k] = bf16(in[k][n]), in is [768][768] f32 row-major
__global__ void cvt_wT_kernel(const float* __restrict__ in, u16* __restrict__ out) {
  __shared__ float tile[64][65];
  const int k0 = blockIdx.x * 64, n0 = blockIdx.y * 64;
  const int t = threadIdx.x;
  const int tr = t >> 6, tc = t & 63;
#pragma unroll
  for (int i = 0; i < 16; ++i) {
    int row = i * 4 + tr;
    tile[row][tc] = in[(size_t)(k0 + row) * 768 + n0 + tc];
  }
  __syncthreads();
#pragma unroll
  for (int i = 0; i < 16; ++i) {
    int row = i * 4 + tr;
    out[(size_t)(n0 + row) * 768 + k0 + tc] = f2bf(tile[tc][row]);
  }
}

// bias in bf16 fragment layout: bp[(kb*577 + q)*8 + j] = log2e * bias(q, k=kb*8+j)
// matches the attention lane layout: one 16B load per (lane, q-group, tile).
__global__ void bias_kernel(const float* __restrict__ table, u16* __restrict__ bp) {
  int idx = blockIdx.x * 256 + threadIdx.x;
  if (idx >= 577 * 76) return;
  int q = idx / 76, kb = idx - q * 76;
  u16 o8[8];
#pragma unroll
  for (int j = 0; j < 8; ++j) {
    int k = kb * 8 + j;
    float v = 0.f;
    if (k <= 576) {
      int id;
      if (q == 0 && k == 0) id = 9;
      else if (q == 0) id = 10;
      else if (k == 0) id = 11;
      else {
        int qy = (q - 1) / 24, qx = (q - 1) % 24;
        int ky = (k - 1) / 24, kx = (k - 1) % 24;
        int ry = qy - ky; ry = ry < -1 ? -1 : (ry > 1 ? 1 : ry);
        int rx = qx - kx; rx = rx < -1 ? -1 : (rx > 1 ? 1 : rx);
        id = (ry + 1) * 3 + (rx + 1);
      }
      v = table[id] * 1.4426950408889634f;
    }
    o8[j] = f2bf(v);
  }
  *(uint4*)(bp + ((size_t)kb * 577 + q) * 8) = *(const uint4*)o8;
}

// v [bh][577][64] -> vT [bh][64][608] via LDS tile (pad cols left as memset zeros)
__global__ __launch_bounds__(256) void transp_v(const u16* __restrict__ v, u16* __restrict__ vT) {
  __shared__ u16 tile[64][65];
  const int bh = blockIdx.x / 10, st = blockIdx.x - (blockIdx.x / 10) * 10;
  const int s0 = st * 64;
  const int t = threadIdx.x;
  const int rq = t >> 6, c = t & 63;
  const u16* vsrc = v + (size_t)bh * 577 * 64;
#pragma unroll
  for (int i = 0; i < 16; ++i) {
    int row = i * 4 + rq;
    int s = s0 + row;
    tile[row][c] = (s < 577) ? vsrc[(size_t)s * 64 + c] : (u16)0;
  }
  __syncthreads();
  u16* vdst = vT + (size_t)bh * 64 * 608;
#pragma unroll
  for (int i = 0; i < 16; ++i) {
    int drow = i * 4 + rq;
    int scol = s0 + c;
    if (scol < 577) vdst[(size_t)drow * 608 + scol] = tile[c][drow];
  }
}

// ---------------- GEMM (128x128 tile, BK=32, 2-phase dbuf, global_load_lds) ----------------

template <int MODE>
__global__ __launch_bounds__(256) void gemm_kernel(
    const u16* __restrict__ A, const u16* __restrict__ BT,
    const int M, const int NBN,
    float* __restrict__ outF, const float* __restrict__ bvec,
    u16* __restrict__ qarr, u16* __restrict__ karr, u16* __restrict__ varr) {
  constexpr int K = 768;
  __shared__ u16 As[2][128 * 32];
  __shared__ u16 Bs[2][128 * 32];

  const int bid = blockIdx.x;
  const int nb = bid % NBN, mb = bid / NBN;
  const int tid = threadIdx.x;
  const int w = tid >> 6, l = tid & 63;
  const int wr = w >> 1, wc = w & 1;
  const int l15 = l & 15, l4 = l >> 4;
  const int m0 = mb * 128, n0 = nb * 128;

  floatx4 acc[4][4];
#pragma unroll
  for (int i = 0; i < 4; ++i)
#pragma unroll
    for (int j = 0; j < 4; ++j) acc[i][j] = 0.f;

  const int trow = tid >> 2;
  const int tk = (tid & 3) * 8;

  auto stage = [&](int buf, int kt) {
    const int k0 = kt * 32;
#pragma unroll
    for (int i = 0; i < 2; ++i) {
      int row = i * 64 + trow;
      int ar = m0 + row; if (ar >= M) ar = M - 1;
      gload16(A + (size_t)ar * K + k0 + tk, &As[buf][row * 32 + tk]);
      int br = n0 + row;
      gload16(BT + (size_t)br * K + k0 + tk, &Bs[buf][row * 32 + tk]);
    }
  };

  stage(0, 0);
  __syncthreads();
  int cur = 0;
  for (int kt = 0; kt < 24; ++kt) {
    if (kt + 1 < 24) stage(cur ^ 1, kt + 1);
    short8 af[4], bf[4];
#pragma unroll
    for (int mi = 0; mi < 4; ++mi)
      af[mi] = *(const short8*)&As[cur][(wr * 64 + mi * 16 + l15) * 32 + l4 * 8];
#pragma unroll
    for (int ni = 0; ni < 4; ++ni)
      bf[ni] = *(const short8*)&Bs[cur][(wc * 64 + ni * 16 + l15) * 32 + l4 * 8];
#pragma unroll
    for (int mi = 0; mi < 4; ++mi)
#pragma unroll
      for (int ni = 0; ni < 4; ++ni)
        acc[mi][ni] = MFMA16(af[mi], bf[ni], acc[mi][ni]);
    __syncthreads();
    cur ^= 1;
  }

#pragma unroll
  for (int mi = 0; mi < 4; ++mi) {
#pragma unroll
    for (int i = 0; i < 4; ++i) {
      const int mrow = m0 + wr * 64 + mi * 16 + l4 * 4 + i;
      if (mrow >= M) continue;
      if constexpr (MODE == 0) {
        const int bq = mrow / 577;
        const int sq = mrow - bq * 577;
#pragma unroll
        for (int ni = 0; ni < 4; ++ni) {
          const int ncol = n0 + wc * 64 + ni * 16 + l15;
          const float val = acc[mi][ni][i];
          const int proj = ncol / 768;
          const int nn = ncol - proj * 768;
          const int h = nn >> 6, d = nn & 63;
          const size_t bh = (size_t)bq * 12 + h;
          // q pre-scaled by 0.125 * log2(e) -> softmax runs in exp2 domain
          if (proj == 0)      qarr[(bh * 577 + sq) * 64 + d] = f2bf(val * 0.18033688011112042f);
          else if (proj == 1) karr[(bh * 577 + sq) * 64 + d] = f2bf(val);
          else                varr[(bh * 577 + sq) * 64 + d] = f2bf(val);
        }
      } else {
#pragma unroll
        for (int ni = 0; ni < 4; ++ni) {
          const int ncol = n0 + wc * 64 + ni * 16 + l15;
          outF[(size_t)mrow * 768 + ncol] = acc[mi][ni][i] + bvec[ncol];
        }
      }
    }
  }
}

// ---------------- fused flash attention (LDS-staged K/V, swapped QK^T) ----------------
// K tile [32 kv][64 d] and V tile [64 d][32 kv] staged ONCE per block into LDS with
// global_load_lds (linear LDS dest; the XOR slot swizzle is applied to the GLOBAL
// source address, m173 pattern), double-buffered. All 4 waves share the tiles.
// Bias comes from the bf16 fragment-layout table: one 16B coalesced load per (g, tile).

__global__ __launch_bounds__(256, 3) void attn_kernel(
    const u16* __restrict__ qg, const u16* __restrict__ kg,
    const u16* __restrict__ vT, const u16* __restrict__ bp,
    u16* __restrict__ xa) {
  // XCD swizzle: 1920 = 8 * 240; all 5 q-blocks of a (b,h) land on one XCD.
  const int bid = (blockIdx.x & 7) * 240 + (blockIdx.x >> 3);
  const int bh = bid / 5, qblk = bid - bh * 5;
  const int tid = threadIdx.x;
  const int w = tid >> 6, l = tid & 63;
  const int l15 = l & 15, l4 = l >> 4;
  const int qbase = qblk * 128 + w * 32;

  const u16* qh = qg + (size_t)bh * 577 * 64;
  const u16* kh = kg + (size_t)bh * 577 * 64;
  const u16* vh = vT + (size_t)bh * 64 * 608;

  __shared__ u16 Ks[2][32 * 64];
  __shared__ u16 Vs[2][32 * 64];

  // ---- staging lane constants (each wave stages rows w*8..w*8+7 of each tile) ----
  const int e_ = l >> 3;                    // 0..7
  const int s_ = l & 7;                     // slot 0..7
  const int Rk = w * 8 + e_;                // K tile row
  const int kbK = s_ ^ ((4 * w + (e_ & 3)) & 7);   // swizzled d-block for K source
  const int dpV = w * 8 + e_;               // V tile row-pair
  const int dV = 2 * dpV + (s_ >> 2);       // d index
  const int kvV = ((s_ & 3) ^ (e_ & 3)) * 8;  // swizzled kv offset for V source

  // ---- read-side offsets (elems, constant per lane) ----
  const int sig = ((l15 >> 2) << 3) + (l15 & 3);
  const int sg = l15 & 7;
  const int offA0 = sig * 64 + ((l4 ^ sg)) * 8;
  const int offA1 = sig * 64 + (((l4 | 4) ^ sg)) * 8;
  const int offA2 = offA0 + 256;
  const int offA3 = offA1 + 256;
  const int dpr = l15 >> 1;
  const int offV = dpr * 64 + (((l15 & 1) << 2) + (l4 ^ (dpr & 3))) * 8;

  short8 qf[2][2];
  int bq[2];
#pragma unroll
  for (int g = 0; g < 2; ++g) {
    int qr = qbase + g * 16 + l15; if (qr > 576) qr = 576;
    bq[g] = qr;
    qf[g][0] = *(const short8*)(qh + qr * 64 + l4 * 8);
    qf[g][1] = *(const short8*)(qh + qr * 64 + 32 + l4 * 8);
  }

  floatx4 o[2][4];
  float m[2] = {-1e30f, -1e30f}, lsum[2] = {0.f, 0.f};
#pragma unroll
  for (int g = 0; g < 2; ++g)
#pragma unroll
    for (int d = 0; d < 4; ++d) o[g][d] = 0.f;

  // prologue: stage tile 0, prefetch bias tile 0
  {
    int kr = Rk; if (kr > 576) kr = 576;
    gload16(kh + (size_t)kr * 64 + kbK * 8, &Ks[0][w * 512 + l * 8]);
    gload16(vh + (size_t)dV * 608 + kvV, &Vs[0][w * 512 + l * 8]);
  }
  uint4 bc0 = *(const uint4*)(bp + ((size_t)l4 * 577 + bq[0]) * 8);
  uint4 bc1 = *(const uint4*)(bp + ((size_t)l4 * 577 + bq[1]) * 8);
  __syncthreads();

  for (int t = 0; t < 19; ++t) {
    const int cur = t & 1;
    const int kvb = t * 32;

    // stage tile t+1 into the other buffer; prefetch bias t+1
    uint4 nb0 = bc0, nb1 = bc1;
    if (t < 18) {
      const int nkvb = kvb + 32;
      int kr = nkvb + Rk; if (kr > 576) kr = 576;
      gload16(kh + (size_t)kr * 64 + kbK * 8, &Ks[cur ^ 1][w * 512 + l * 8]);
      gload16(vh + (size_t)dV * 608 + nkvb + kvV, &Vs[cur ^ 1][w * 512 + l * 8]);
      const int nkb = (t + 1) * 4 + l4;
      nb0 = *(const uint4*)(bp + ((size_t)nkb * 577 + bq[0]) * 8);
      nb1 = *(const uint4*)(bp + ((size_t)nkb * 577 + bq[1]) * 8);
    }

    // fragments from LDS
    const u16* kb_ = &Ks[cur][0];
    const short8 A0 = *(const short8*)(kb_ + offA0);
    const short8 A1 = *(const short8*)(kb_ + offA1);
    const short8 A2 = *(const short8*)(kb_ + offA2);
    const short8 A3 = *(const short8*)(kb_ + offA3);
    const u16* vb_ = &Vs[cur][0];
    const short8 vf0 = *(const short8*)(vb_ + offV);
    const short8 vf1 = *(const short8*)(vb_ + offV + 512);
    const short8 vf2 = *(const short8*)(vb_ + offV + 1024);
    const short8 vf3 = *(const short8*)(vb_ + offV + 1536);

    float v0[8], v1[8];
    {
      floatx4 s0 = 0.f, s1 = 0.f, s2 = 0.f, s3 = 0.f;
      __builtin_amdgcn_s_setprio(1);
      s0 = MFMA16(A0, qf[0][0], s0);
      s0 = MFMA16(A1, qf[0][1], s0);
      s1 = MFMA16(A2, qf[0][0], s1);
      s1 = MFMA16(A3, qf[0][1], s1);
      s2 = MFMA16(A0, qf[1][0], s2);
      s2 = MFMA16(A1, qf[1][1], s2);
      s3 = MFMA16(A2, qf[1][0], s3);
      s3 = MFMA16(A3, qf[1][1], s3);
      __builtin_amdgcn_s_setprio(0);
      v0[0] = s0[0] + bflo(bc0.x); v0[1] = s0[1] + bfhi(bc0.x);
      v0[2] = s0[2] + bflo(bc0.y); v0[3] = s0[3] + bfhi(bc0.y);
      v0[4] = s1[0] + bflo(bc0.z); v0[5] = s1[1] + bfhi(bc0.z);
      v0[6] = s1[2] + bflo(bc0.w); v0[7] = s1[3] + bfhi(bc0.w);
      v1[0] = s2[0] + bflo(bc1.x); v1[1] = s2[1] + bfhi(bc1.x);
      v1[2] = s2[2] + bflo(bc1.y); v1[3] = s2[3] + bfhi(bc1.y);
      v1[4] = s3[0] + bflo(bc1.z); v1[5] = s3[1] + bfhi(bc1.z);
      v1[6] = s3[2] + bflo(bc1.w); v1[7] = s3[3] + bfhi(bc1.w);
    }

    if (t == 18) {
      const int kg0 = kvb + l4 * 8;
#pragma unroll
      for (int j = 0; j < 8; ++j)
        if (kg0 + j > 576) { v0[j] = -1e30f; v1[j] = -1e30f; }
    }

    float vmA = fmaxf(fmaxf(fmaxf(v0[0], v0[1]), fmaxf(v0[2], v0[3])),
                      fmaxf(fmaxf(v0[4], v0[5]), fmaxf(v0[6], v0[7])));
    float vmB = fmaxf(fmaxf(fmaxf(v1[0], v1[1]), fmaxf(v1[2], v1[3])),
                      fmaxf(fmaxf(v1[4], v1[5]), fmaxf(v1[6], v1[7])));
    vmA = fmaxf(vmA, __shfl_xor(vmA, 16)); vmA = fmaxf(vmA, __shfl_xor(vmA, 32));
    vmB = fmaxf(vmB, __shfl_xor(vmB, 16)); vmB = fmaxf(vmB, __shfl_xor(vmB, 32));

    // T13 defer-max: rescale only when some row max grew past THR=8 (log2 units)
    if (__any((vmA > m[0] + 8.f) || (vmB > m[1] + 8.f))) {
      const float mn0 = fmaxf(m[0], vmA), mn1 = fmaxf(m[1], vmB);
      const float sc0 = exp2hw(m[0] - mn0), sc1 = exp2hw(m[1] - mn1);
      lsum[0] *= sc0; lsum[1] *= sc1;
#pragma unroll
      for (int d = 0; d < 4; ++d) { o[0][d] *= sc0; o[1][d] *= sc1; }
      m[0] = mn0; m[1] = mn1;
    }

    float e0[8], e1[8];
    float rs0 = 0.f, rs1 = 0.f;
#pragma unroll
    for (int j = 0; j < 8; ++j) { e0[j] = exp2hw(v0[j] - m[0]); rs0 += e0[j]; }
#pragma unroll
    for (int j = 0; j < 8; ++j) { e1[j] = exp2hw(v1[j] - m[1]); rs1 += e1[j]; }
    rs0 += __shfl_xor(rs0, 16); rs0 += __shfl_xor(rs0, 32);
    rs1 += __shfl_xor(rs1, 16); rs1 += __shfl_xor(rs1, 32);
    lsum[0] += rs0; lsum[1] += rs1;

    union PU { unsigned u[4]; short8 s; };
    PU p0, p1;
#pragma unroll
    for (int j = 0; j < 4; ++j) {
      p0.u[j] = cvtpk_bf16(e0[2 * j], e0[2 * j + 1]);
      p1.u[j] = cvtpk_bf16(e1[2 * j], e1[2 * j + 1]);
    }

    __builtin_amdgcn_s_setprio(1);
    o[0][0] = MFMA16(vf0, p0.s, o[0][0]);
    o[1][0] = MFMA16(vf0, p1.s, o[1][0]);
    o[0][1] = MFMA16(vf1, p0.s, o[0][1]);
    o[1][1] = MFMA16(vf1, p1.s, o[1][1]);
    o[0][2] = MFMA16(vf2, p0.s, o[0][2]);
    o[1][2] = MFMA16(vf2, p1.s, o[1][2]);
    o[0][3] = MFMA16(vf3, p0.s, o[0][3]);
    o[1][3] = MFMA16(vf3, p1.s, o[1][3]);
    __builtin_amdgcn_s_setprio(0);

    bc0 = nb0; bc1 = nb1;
    __syncthreads();  // drains vmcnt (staging t+1 done) + all waves done reading buf cur
  }

  const int b = bh / 12, h = bh - (bh / 12) * 12;
#pragma unroll
  for (int g = 0; g < 2; ++g) {
    const int gq = qbase + g * 16 + l15;
    if (gq < 577) {
      const float inv = 1.f / lsum[g];
      u16* op = xa + ((size_t)(b * 577 + gq)) * 768 + h * 64 + l4 * 4;
#pragma unroll
      for (int d = 0; d < 4; ++d) {
        unsigned w0 = cvtpk_bf16(o[g][d][0] * inv, o[g][d][1] * inv);
        unsigned w1 = cvtpk_bf16(o[g][d][2] * inv, o[g][d][3] * inv);
        *(unsigned*)(op + d * 16) = w0;
        *(unsigned*)(op + d * 16 + 2) = w1;
      }
    }
  }
}

// ---------------- launch ----------------

extern "C" void kernel_launch(void* const* d_in, const int* in_sizes, int n_in,
                              void* d_out, int out_size, void* d_ws, size_t ws_size,
                              hipStream_t stream) {
  const float* x  = (const float*)d_in[0];
  const float* Wq = (const float*)d_in[1];
  const float* Wk = (const float*)d_in[2];
  const float* Wv = (const float*)d_in[3];
  const float* Wo = (const float*)d_in[4];
  const float* bo = (const float*)d_in[5];
  const float* bt = (const float*)d_in[6];
  float* out = (float*)d_out;

  char* ws = (char*)d_ws;
  size_t off = 0;
  auto alloc = [&](size_t bytes) {
    void* p = ws + off;
    off += (bytes + 255) & ~(size_t)255;
    return p;
  };
  u16* xb   = (u16*)alloc((size_t)18464 * 768 * 2);   // reused as xa after GEMM0
  u16* WT   = (u16*)alloc((size_t)2304 * 768 * 2);
  u16* WoT  = (u16*)alloc((size_t)768 * 768 * 2);
  u16* qa   = (u16*)alloc((size_t)384 * 577 * 64 * 2);
  u16* ka   = (u16*)alloc((size_t)384 * 577 * 64 * 2);
  u16* vT   = (u16*)alloc((size_t)384 * 64 * 608 * 2);
  u16* biasPk = (u16*)alloc((size_t)76 * 577 * 8 * 2);
  // V row-major scratch lives in d_out (56.7 MB f32) — fully overwritten by GEMM1 later.
  u16* va   = (u16*)d_out;
  (void)ws_size; (void)in_sizes; (void)n_in; (void)out_size;

  (void)hipMemsetAsync(vT, 0, (size_t)384 * 64 * 608 * 2, stream);

  cvt_x_kernel<<<(18464 * 768 / 4 + 255) / 256, 256, 0, stream>>>(x, xb, 18464 * 768 / 4);
  dim3 tg(12, 12);
  cvt_wT_kernel<<<tg, 256, 0, stream>>>(Wq, WT);
  cvt_wT_kernel<<<tg, 256, 0, stream>>>(Wk, WT + (size_t)768 * 768);
  cvt_wT_kernel<<<tg, 256, 0, stream>>>(Wv, WT + (size_t)2 * 768 * 768);
  cvt_wT_kernel<<<tg, 256, 0, stream>>>(Wo, WoT);
  bias_kernel<<<(577 * 76 + 255) / 256, 256, 0, stream>>>(bt, biasPk);

  // QKV projection: [18464][768] x [768][2304] -> q,k,v (all row-major, coalesced stores)
  gemm_kernel<0><<<145 * 18, 256, 0, stream>>>(xb, WT, 18464, 18,
                                               nullptr, nullptr, qa, ka, va);
  // v -> vT
  transp_v<<<3840, 256, 0, stream>>>(va, vT);
  // attention -> xa (reuse xb region)
  attn_kernel<<<1920, 256, 0, stream>>>(qa, ka, vT, biasPk, xb);
  // output projection: xa x WoT + bo -> out (f32)
  gemm_kernel<1><<<145 * 6, 256, 0, stream>>>(xb, WoT, 18464, 6,
                                              out, bo, nullptr, nullptr, nullptr);
}

// Round 6
// 258.944 us; speedup vs baseline: 1.7446x; 1.1496x over previous
//
#include <hip/hip_runtime.h>

typedef unsigned short u16;
typedef short short8 __attribute__((ext_vector_type(8)));
typedef float floatx4 __attribute__((ext_vector_type(4)));

#define MFMA16(a, b, c) __builtin_amdgcn_mfma_f32_16x16x32_bf16((a), (b), (c), 0, 0, 0)

__device__ __forceinline__ u16 f2bf(float f) {
  unsigned u = __builtin_bit_cast(unsigned, f);
  u = (u + 0x7fffu + ((u >> 16) & 1u)) >> 16;
  return (u16)u;
}

__device__ __forceinline__ float exp2hw(float x) {
  float r; asm("v_exp_f32 %0, %1" : "=v"(r) : "v"(x)); return r;
}

__device__ __forceinline__ unsigned cvtpk_bf16(float lo, float hi) {
  unsigned r;
  asm("v_cvt_pk_bf16_f32 %0, %1, %2" : "=v"(r) : "v"(lo), "v"(hi));
  return r;
}

__device__ __forceinline__ float bflo(unsigned u) {
  return __builtin_bit_cast(float, u << 16);
}
__device__ __forceinline__ float bfhi(unsigned u) {
  return __builtin_bit_cast(float, u & 0xffff0000u);
}

__device__ __forceinline__ void gload16(const void* g, void* l) {
  typedef __attribute__((address_space(1))) const void GV;
  typedef __attribute__((address_space(3))) void LV;
  __builtin_amdgcn_global_load_lds((GV*)g, (LV*)l, 16, 0, 0);
}

// ---------------- convert / prep kernels ----------------

__global__ void cvt_x_kernel(const float* __restrict__ x, u16* __restrict__ xb, int n4) {
  int i = blockIdx.x * 256 + threadIdx.x;
  if (i >= n4) return;
  float4 v = ((const float4*)x)[i];
  ushort4 r; r.x = f2bf(v.x); r.y = f2bf(v.y); r.z = f2bf(v.z); r.w = f2bf(v.w);
  ((ushort4*)xb)[i] = r;
}

// out[n][k] = bf16(in[k][n]), in is [768][768] f32 row-major
__global__ void cvt_wT_kernel(const float* __restrict__ in, u16* __restrict__ out) {
  __shared__ float tile[64][65];
  const int k0 = blockIdx.x * 64, n0 = blockIdx.y * 64;
  const int t = threadIdx.x;
  const int tr = t >> 6, tc = t & 63;
#pragma unroll
  for (int i = 0; i < 16; ++i) {
    int row = i * 4 + tr;
    tile[row][tc] = in[(size_t)(k0 + row) * 768 + n0 + tc];
  }
  __syncthreads();
#pragma unroll
  for (int i = 0; i < 16; ++i) {
    int row = i * 4 + tr;
    out[(size_t)(n0 + row) * 768 + k0 + tc] = f2bf(tile[tc][row]);
  }
}

// bias in bf16 fragment layout: bp[(kb*577 + q)*8 + j] = log2e * bias(q, k=kb*8+j)
__global__ void bias_kernel(const float* __restrict__ table, u16* __restrict__ bp) {
  int idx = blockIdx.x * 256 + threadIdx.x;
  if (idx >= 577 * 76) return;
  int q = idx / 76, kb = idx - q * 76;
  u16 o8[8];
#pragma unroll
  for (int j = 0; j < 8; ++j) {
    int k = kb * 8 + j;
    float v = 0.f;
    if (k <= 576) {
      int id;
      if (q == 0 && k == 0) id = 9;
      else if (q == 0) id = 10;
      else if (k == 0) id = 11;
      else {
        int qy = (q - 1) / 24, qx = (q - 1) % 24;
        int ky = (k - 1) / 24, kx = (k - 1) % 24;
        int ry = qy - ky; ry = ry < -1 ? -1 : (ry > 1 ? 1 : ry);
        int rx = qx - kx; rx = rx < -1 ? -1 : (rx > 1 ? 1 : rx);
        id = (ry + 1) * 3 + (rx + 1);
      }
      v = table[id] * 1.4426950408889634f;
    }
    o8[j] = f2bf(v);
  }
  *(uint4*)(bp + ((size_t)kb * 577 + q) * 8) = *(const uint4*)o8;
}

// zero the 31 pad columns (sq 577..607) of vT so pad reads are finite-zero.
__global__ void zero_vpad(u16* __restrict__ vT) {
  int i = blockIdx.x * 256 + threadIdx.x;
  if (i >= 384 * 64 * 31) return;
  int row = i / 31, c = i - (i / 31) * 31;
  vT[(size_t)row * 608 + 577 + c] = 0;
}

// ---------------- GEMM (128x128 tile, BK=32, 2-phase dbuf, global_load_lds) ----------------
// MODE 0: QKV — LDS-bounce epilogue; q/k row-major coalesced 16B stores; v written
// directly TRANSPOSED into vT with lane-consecutive sq (coalesced 2B stores).
// MODE 1: out = val + bvec[n] (f32 direct).

template <int MODE>
__global__ __launch_bounds__(256) void gemm_kernel(
    const u16* __restrict__ A, const u16* __restrict__ BT,
    const int M, const int NBN,
    float* __restrict__ outF, const float* __restrict__ bvec,
    u16* __restrict__ qarr, u16* __restrict__ karr, u16* __restrict__ vTa) {
  constexpr int K = 768;
  // staging: As [2][128*32] + Bs [2][128*32] = 16384 u16; epilogue bounce Cs [128][136]
  __shared__ __align__(16) u16 smem[17408];
  u16* As = smem;
  u16* Bs = smem + 8192;
  u16* Cs = smem;

  const int bid = blockIdx.x;
  const int nb = bid % NBN, mb = bid / NBN;
  const int tid = threadIdx.x;
  const int w = tid >> 6, l = tid & 63;
  const int wr = w >> 1, wc = w & 1;
  const int l15 = l & 15, l4 = l >> 4;
  const int m0 = mb * 128, n0 = nb * 128;

  floatx4 acc[4][4];
#pragma unroll
  for (int i = 0; i < 4; ++i)
#pragma unroll
    for (int j = 0; j < 4; ++j) acc[i][j] = 0.f;

  const int trow = tid >> 2;
  const int tk = (tid & 3) * 8;

  auto stage = [&](int buf, int kt) {
    const int k0 = kt * 32;
#pragma unroll
    for (int i = 0; i < 2; ++i) {
      int row = i * 64 + trow;
      int ar = m0 + row; if (ar >= M) ar = M - 1;
      gload16(A + (size_t)ar * K + k0 + tk, &As[buf * 4096 + row * 32 + tk]);
      int br = n0 + row;
      gload16(BT + (size_t)br * K + k0 + tk, &Bs[buf * 4096 + row * 32 + tk]);
    }
  };

  stage(0, 0);
  __syncthreads();
  int cur = 0;
  for (int kt = 0; kt < 24; ++kt) {
    if (kt + 1 < 24) stage(cur ^ 1, kt + 1);
    short8 af[4], bf[4];
#pragma unroll
    for (int mi = 0; mi < 4; ++mi)
      af[mi] = *(const short8*)&As[cur * 4096 + (wr * 64 + mi * 16 + l15) * 32 + l4 * 8];
#pragma unroll
    for (int ni = 0; ni < 4; ++ni)
      bf[ni] = *(const short8*)&Bs[cur * 4096 + (wc * 64 + ni * 16 + l15) * 32 + l4 * 8];
#pragma unroll
    for (int mi = 0; mi < 4; ++mi)
#pragma unroll
      for (int ni = 0; ni < 4; ++ni)
        acc[mi][ni] = MFMA16(af[mi], bf[ni], acc[mi][ni]);
    __syncthreads();
    cur ^= 1;
  }

  if constexpr (MODE == 0) {
    const int proj = nb / 6;            // 0=q 1=k 2=v (768/BN = 6 blocks per proj)
    const int h0 = (nb - proj * 6) * 2; // head for cols 0..63; +1 for cols 64..127
    const float qs = (proj == 0) ? 0.18033688011112042f : 1.0f;
    // acc -> Cs (bf16), padded stride 136 keeps 16B alignment per row
#pragma unroll
    for (int mi = 0; mi < 4; ++mi)
#pragma unroll
      for (int i = 0; i < 4; ++i) {
        const int rloc = wr * 64 + mi * 16 + l4 * 4 + i;
#pragma unroll
        for (int ni = 0; ni < 4; ++ni) {
          const int cloc = wc * 64 + ni * 16 + l15;
          Cs[rloc * 136 + cloc] = f2bf(acc[mi][ni][i] * qs);
        }
      }
    __syncthreads();

    if (proj < 2) {
      u16* dst = (proj == 0) ? qarr : karr;
      const int r = tid >> 1, half = tid & 1;
      const int mrow = m0 + r;
      if (mrow < M) {
        const int bq = mrow / 577, sq = mrow - bq * 577;
        u16* base = dst + ((size_t)(bq * 12 + h0 + half) * 577 + sq) * 64;
        const u16* src = Cs + r * 136 + half * 64;
#pragma unroll
        for (int j = 0; j < 8; ++j)
          *(uint4*)(base + j * 8) = *(const uint4*)(src + j * 8);
      }
    } else {
      const int rr = tid & 127, chalf = tid >> 7;
      const int mrow = m0 + rr;
      if (mrow < M) {
        const int bq = mrow / 577, sq = mrow - bq * 577;
        u16* vbase = vTa + ((size_t)(bq * 12 + h0 + chalf) * 64) * 608 + sq;
        const u16* src = Cs + rr * 136 + chalf * 64;
#pragma unroll
        for (int dc = 0; dc < 8; ++dc) {
          const short8 vv = *(const short8*)(src + dc * 8);
#pragma unroll
          for (int jj = 0; jj < 8; ++jj)
            vbase[(size_t)(dc * 8 + jj) * 608] = (u16)vv[jj];
        }
      }
    }
  } else {
#pragma unroll
    for (int mi = 0; mi < 4; ++mi) {
#pragma unroll
      for (int i = 0; i < 4; ++i) {
        const int mrow = m0 + wr * 64 + mi * 16 + l4 * 4 + i;
        if (mrow >= M) continue;
#pragma unroll
        for (int ni = 0; ni < 4; ++ni) {
          const int ncol = n0 + wc * 64 + ni * 16 + l15;
          outF[(size_t)mrow * 768 + ncol] = acc[mi][ni][i] + bvec[ncol];
        }
      }
    }
  }
}

// ---------------- fused flash attention (LDS-staged K/V, swapped QK^T) ----------------

__global__ __launch_bounds__(256, 3) void attn_kernel(
    const u16* __restrict__ qg, const u16* __restrict__ kg,
    const u16* __restrict__ vT, const u16* __restrict__ bp,
    u16* __restrict__ xa) {
  // XCD swizzle: 1920 = 8 * 240; all 5 q-blocks of a (b,h) land on one XCD.
  const int bid = (blockIdx.x & 7) * 240 + (blockIdx.x >> 3);
  const int bh = bid / 5, qblk = bid - bh * 5;
  const int tid = threadIdx.x;
  const int w = tid >> 6, l = tid & 63;
  const int l15 = l & 15, l4 = l >> 4;
  const int qbase = qblk * 128 + w * 32;

  const u16* qh = qg + (size_t)bh * 577 * 64;
  const u16* kh = kg + (size_t)bh * 577 * 64;
  const u16* vh = vT + (size_t)bh * 64 * 608;

  __shared__ u16 Ks[2][32 * 64];
  __shared__ u16 Vs[2][32 * 64];

  const int e_ = l >> 3;
  const int s_ = l & 7;
  const int Rk = w * 8 + e_;
  const int kbK = s_ ^ ((4 * w + (e_ & 3)) & 7);
  const int dpV = w * 8 + e_;
  const int dV = 2 * dpV + (s_ >> 2);
  const int kvV = ((s_ & 3) ^ (e_ & 3)) * 8;

  const int sig = ((l15 >> 2) << 3) + (l15 & 3);
  const int sg = l15 & 7;
  const int offA0 = sig * 64 + ((l4 ^ sg)) * 8;
  const int offA1 = sig * 64 + (((l4 | 4) ^ sg)) * 8;
  const int offA2 = offA0 + 256;
  const int offA3 = offA1 + 256;
  const int dpr = l15 >> 1;
  const int offV = dpr * 64 + (((l15 & 1) << 2) + (l4 ^ (dpr & 3))) * 8;

  short8 qf[2][2];
  int bq[2];
#pragma unroll
  for (int g = 0; g < 2; ++g) {
    int qr = qbase + g * 16 + l15; if (qr > 576) qr = 576;
    bq[g] = qr;
    qf[g][0] = *(const short8*)(qh + qr * 64 + l4 * 8);
    qf[g][1] = *(const short8*)(qh + qr * 64 + 32 + l4 * 8);
  }

  floatx4 o[2][4];
  float m[2] = {-1e30f, -1e30f}, lsum[2] = {0.f, 0.f};
#pragma unroll
  for (int g = 0; g < 2; ++g)
#pragma unroll
    for (int d = 0; d < 4; ++d) o[g][d] = 0.f;

  {
    int kr = Rk; if (kr > 576) kr = 576;
    gload16(kh + (size_t)kr * 64 + kbK * 8, &Ks[0][w * 512 + l * 8]);
    gload16(vh + (size_t)dV * 608 + kvV, &Vs[0][w * 512 + l * 8]);
  }
  uint4 bc0 = *(const uint4*)(bp + ((size_t)l4 * 577 + bq[0]) * 8);
  uint4 bc1 = *(const uint4*)(bp + ((size_t)l4 * 577 + bq[1]) * 8);
  __syncthreads();

  for (int t = 0; t < 19; ++t) {
    const int cur = t & 1;
    const int kvb = t * 32;

    uint4 nb0 = bc0, nb1 = bc1;
    if (t < 18) {
      const int nkvb = kvb + 32;
      int kr = nkvb + Rk; if (kr > 576) kr = 576;
      gload16(kh + (size_t)kr * 64 + kbK * 8, &Ks[cur ^ 1][w * 512 + l * 8]);
      gload16(vh + (size_t)dV * 608 + nkvb + kvV, &Vs[cur ^ 1][w * 512 + l * 8]);
      const int nkb = (t + 1) * 4 + l4;
      nb0 = *(const uint4*)(bp + ((size_t)nkb * 577 + bq[0]) * 8);
      nb1 = *(const uint4*)(bp + ((size_t)nkb * 577 + bq[1]) * 8);
    }

    const u16* kb_ = &Ks[cur][0];
    const short8 A0 = *(const short8*)(kb_ + offA0);
    const short8 A1 = *(const short8*)(kb_ + offA1);
    const short8 A2 = *(const short8*)(kb_ + offA2);
    const short8 A3 = *(const short8*)(kb_ + offA3);
    const u16* vb_ = &Vs[cur][0];
    const short8 vf0 = *(const short8*)(vb_ + offV);
    const short8 vf1 = *(const short8*)(vb_ + offV + 512);
    const short8 vf2 = *(const short8*)(vb_ + offV + 1024);
    const short8 vf3 = *(const short8*)(vb_ + offV + 1536);

    float v0[8], v1[8];
    {
      floatx4 s0 = 0.f, s1 = 0.f, s2 = 0.f, s3 = 0.f;
      __builtin_amdgcn_s_setprio(1);
      s0 = MFMA16(A0, qf[0][0], s0);
      s0 = MFMA16(A1, qf[0][1], s0);
      s1 = MFMA16(A2, qf[0][0], s1);
      s1 = MFMA16(A3, qf[0][1], s1);
      s2 = MFMA16(A0, qf[1][0], s2);
      s2 = MFMA16(A1, qf[1][1], s2);
      s3 = MFMA16(A2, qf[1][0], s3);
      s3 = MFMA16(A3, qf[1][1], s3);
      __builtin_amdgcn_s_setprio(0);
      v0[0] = s0[0] + bflo(bc0.x); v0[1] = s0[1] + bfhi(bc0.x);
      v0[2] = s0[2] + bflo(bc0.y); v0[3] = s0[3] + bfhi(bc0.y);
      v0[4] = s1[0] + bflo(bc0.z); v0[5] = s1[1] + bfhi(bc0.z);
      v0[6] = s1[2] + bflo(bc0.w); v0[7] = s1[3] + bfhi(bc0.w);
      v1[0] = s2[0] + bflo(bc1.x); v1[1] = s2[1] + bfhi(bc1.x);
      v1[2] = s2[2] + bflo(bc1.y); v1[3] = s2[3] + bfhi(bc1.y);
      v1[4] = s3[0] + bflo(bc1.z); v1[5] = s3[1] + bfhi(bc1.z);
      v1[6] = s3[2] + bflo(bc1.w); v1[7] = s3[3] + bfhi(bc1.w);
    }

    if (t == 18) {
      const int kg0 = kvb + l4 * 8;
#pragma unroll
      for (int j = 0; j < 8; ++j)
        if (kg0 + j > 576) { v0[j] = -1e30f; v1[j] = -1e30f; }
    }

    float vmA = fmaxf(fmaxf(fmaxf(v0[0], v0[1]), fmaxf(v0[2], v0[3])),
                      fmaxf(fmaxf(v0[4], v0[5]), fmaxf(v0[6], v0[7])));
    float vmB = fmaxf(fmaxf(fmaxf(v1[0], v1[1]), fmaxf(v1[2], v1[3])),
                      fmaxf(fmaxf(v1[4], v1[5]), fmaxf(v1[6], v1[7])));
    vmA = fmaxf(vmA, __shfl_xor(vmA, 16)); vmA = fmaxf(vmA, __shfl_xor(vmA, 32));
    vmB = fmaxf(vmB, __shfl_xor(vmB, 16)); vmB = fmaxf(vmB, __shfl_xor(vmB, 32));

    if (__any((vmA > m[0] + 8.f) || (vmB > m[1] + 8.f))) {
      const float mn0 = fmaxf(m[0], vmA), mn1 = fmaxf(m[1], vmB);
      const float sc0 = exp2hw(m[0] - mn0), sc1 = exp2hw(m[1] - mn1);
      lsum[0] *= sc0; lsum[1] *= sc1;
#pragma unroll
      for (int d = 0; d < 4; ++d) { o[0][d] *= sc0; o[1][d] *= sc1; }
      m[0] = mn0; m[1] = mn1;
    }

    float e0[8], e1[8];
    float rs0 = 0.f, rs1 = 0.f;
#pragma unroll
    for (int j = 0; j < 8; ++j) { e0[j] = exp2hw(v0[j] - m[0]); rs0 += e0[j]; }
#pragma unroll
    for (int j = 0; j < 8; ++j) { e1[j] = exp2hw(v1[j] - m[1]); rs1 += e1[j]; }
    rs0 += __shfl_xor(rs0, 16); rs0 += __shfl_xor(rs0, 32);
    rs1 += __shfl_xor(rs1, 16); rs1 += __shfl_xor(rs1, 32);
    lsum[0] += rs0; lsum[1] += rs1;

    union PU { unsigned u[4]; short8 s; };
    PU p0, p1;
#pragma unroll
    for (int j = 0; j < 4; ++j) {
      p0.u[j] = cvtpk_bf16(e0[2 * j], e0[2 * j + 1]);
      p1.u[j] = cvtpk_bf16(e1[2 * j], e1[2 * j + 1]);
    }

    __builtin_amdgcn_s_setprio(1);
    o[0][0] = MFMA16(vf0, p0.s, o[0][0]);
    o[1][0] = MFMA16(vf0, p1.s, o[1][0]);
    o[0][1] = MFMA16(vf1, p0.s, o[0][1]);
    o[1][1] = MFMA16(vf1, p1.s, o[1][1]);
    o[0][2] = MFMA16(vf2, p0.s, o[0][2]);
    o[1][2] = MFMA16(vf2, p1.s, o[1][2]);
    o[0][3] = MFMA16(vf3, p0.s, o[0][3]);
    o[1][3] = MFMA16(vf3, p1.s, o[1][3]);
    __builtin_amdgcn_s_setprio(0);

    bc0 = nb0; bc1 = nb1;
    __syncthreads();
  }

  const int b = bh / 12, h = bh - (bh / 12) * 12;
#pragma unroll
  for (int g = 0; g < 2; ++g) {
    const int gq = qbase + g * 16 + l15;
    if (gq < 577) {
      const float inv = 1.f / lsum[g];
      u16* op = xa + ((size_t)(b * 577 + gq)) * 768 + h * 64 + l4 * 4;
#pragma unroll
      for (int d = 0; d < 4; ++d) {
        unsigned w0 = cvtpk_bf16(o[g][d][0] * inv, o[g][d][1] * inv);
        unsigned w1 = cvtpk_bf16(o[g][d][2] * inv, o[g][d][3] * inv);
        *(unsigned*)(op + d * 16) = w0;
        *(unsigned*)(op + d * 16 + 2) = w1;
      }
    }
  }
}

// ---------------- launch ----------------

extern "C" void kernel_launch(void* const* d_in, const int* in_sizes, int n_in,
                              void* d_out, int out_size, void* d_ws, size_t ws_size,
                              hipStream_t stream) {
  const float* x  = (const float*)d_in[0];
  const float* Wq = (const float*)d_in[1];
  const float* Wk = (const float*)d_in[2];
  const float* Wv = (const float*)d_in[3];
  const float* Wo = (const float*)d_in[4];
  const float* bo = (const float*)d_in[5];
  const float* bt = (const float*)d_in[6];
  float* out = (float*)d_out;

  char* ws = (char*)d_ws;
  size_t off = 0;
  auto alloc = [&](size_t bytes) {
    void* p = ws + off;
    off += (bytes + 255) & ~(size_t)255;
    return p;
  };
  u16* xb   = (u16*)alloc((size_t)18464 * 768 * 2);   // reused as xa after GEMM0
  u16* WT   = (u16*)alloc((size_t)2304 * 768 * 2);
  u16* WoT  = (u16*)alloc((size_t)768 * 768 * 2);
  u16* qa   = (u16*)alloc((size_t)384 * 577 * 64 * 2);
  u16* ka   = (u16*)alloc((size_t)384 * 577 * 64 * 2);
  u16* vT   = (u16*)alloc((size_t)384 * 64 * 608 * 2);
  u16* biasPk = (u16*)alloc((size_t)76 * 577 * 8 * 2);
  (void)ws_size; (void)in_sizes; (void)n_in; (void)out_size;

  zero_vpad<<<(384 * 64 * 31 + 255) / 256, 256, 0, stream>>>(vT);
  cvt_x_kernel<<<(18464 * 768 / 4 + 255) / 256, 256, 0, stream>>>(x, xb, 18464 * 768 / 4);
  dim3 tg(12, 12);
  cvt_wT_kernel<<<tg, 256, 0, stream>>>(Wq, WT);
  cvt_wT_kernel<<<tg, 256, 0, stream>>>(Wk, WT + (size_t)768 * 768);
  cvt_wT_kernel<<<tg, 256, 0, stream>>>(Wv, WT + (size_t)2 * 768 * 768);
  cvt_wT_kernel<<<tg, 256, 0, stream>>>(Wo, WoT);
  bias_kernel<<<(577 * 76 + 255) / 256, 256, 0, stream>>>(bt, biasPk);

  // QKV projection: writes q,k row-major and v directly transposed into vT
  gemm_kernel<0><<<145 * 18, 256, 0, stream>>>(xb, WT, 18464, 18,
                                               nullptr, nullptr, qa, ka, vT);
  // attention -> xa (reuse xb region)
  attn_kernel<<<1920, 256, 0, stream>>>(qa, ka, vT, biasPk, xb);
  // output projection: xa x WoT + bo -> out (f32)
  gemm_kernel<1><<<145 * 6, 256, 0, stream>>>(xb, WoT, 18464, 6,
                                              out, bo, nullptr, nullptr, nullptr);
}

// Round 7
// 247.555 us; speedup vs baseline: 1.8248x; 1.0460x over previous
//
#include <hip/hip_runtime.h>

typedef unsigned short u16;
typedef short short8 __attribute__((ext_vector_type(8)));
typedef float floatx4 __attribute__((ext_vector_type(4)));

#define MFMA16(a, b, c) __builtin_amdgcn_mfma_f32_16x16x32_bf16((a), (b), (c), 0, 0, 0)

__device__ __forceinline__ u16 f2bf(float f) {
  unsigned u = __builtin_bit_cast(unsigned, f);
  u = (u + 0x7fffu + ((u >> 16) & 1u)) >> 16;
  return (u16)u;
}

__device__ __forceinline__ float bf2f(u16 u) {
  return __builtin_bit_cast(float, ((unsigned)u) << 16);
}

__device__ __forceinline__ float exp2hw(float x) {
  float r; asm("v_exp_f32 %0, %1" : "=v"(r) : "v"(x)); return r;
}

__device__ __forceinline__ unsigned cvtpk_bf16(float lo, float hi) {
  unsigned r;
  asm("v_cvt_pk_bf16_f32 %0, %1, %2" : "=v"(r) : "v"(lo), "v"(hi));
  return r;
}

__device__ __forceinline__ float bflo(unsigned u) {
  return __builtin_bit_cast(float, u << 16);
}
__device__ __forceinline__ float bfhi(unsigned u) {
  return __builtin_bit_cast(float, u & 0xffff0000u);
}

__device__ __forceinline__ void gload16(const void* g, void* l) {
  typedef __attribute__((address_space(1))) const void GV;
  typedef __attribute__((address_space(3))) void LV;
  __builtin_amdgcn_global_load_lds((GV*)g, (LV*)l, 16, 0, 0);
}

// ---------------- convert / prep kernels ----------------

__global__ void cvt_x_kernel(const float* __restrict__ x, u16* __restrict__ xb, int n4) {
  int i = blockIdx.x * 256 + threadIdx.x;
  if (i >= n4) return;
  float4 v = ((const float4*)x)[i];
  ushort4 r; r.x = f2bf(v.x); r.y = f2bf(v.y); r.z = f2bf(v.z); r.w = f2bf(v.w);
  ((ushort4*)xb)[i] = r;
}

// out[n][k] = bf16(in[k][n]), in is [768][768] f32 row-major
__global__ void cvt_wT_kernel(const float* __restrict__ in, u16* __restrict__ out) {
  __shared__ float tile[64][65];
  const int k0 = blockIdx.x * 64, n0 = blockIdx.y * 64;
  const int t = threadIdx.x;
  const int tr = t >> 6, tc = t & 63;
#pragma unroll
  for (int i = 0; i < 16; ++i) {
    int row = i * 4 + tr;
    tile[row][tc] = in[(size_t)(k0 + row) * 768 + n0 + tc];
  }
  __syncthreads();
#pragma unroll
  for (int i = 0; i < 16; ++i) {
    int row = i * 4 + tr;
    out[(size_t)(n0 + row) * 768 + k0 + tc] = f2bf(tile[tc][row]);
  }
}

// bias in bf16 fragment layout: bp[(kb*577 + q)*8 + j] = log2e * bias(q, k=kb*8+j)
__global__ void bias_kernel(const float* __restrict__ table, u16* __restrict__ bp) {
  int idx = blockIdx.x * 256 + threadIdx.x;
  if (idx >= 577 * 76) return;
  int q = idx / 76, kb = idx - q * 76;
  u16 o8[8];
#pragma unroll
  for (int j = 0; j < 8; ++j) {
    int k = kb * 8 + j;
    float v = 0.f;
    if (k <= 576) {
      int id;
      if (q == 0 && k == 0) id = 9;
      else if (q == 0) id = 10;
      else if (k == 0) id = 11;
      else {
        int qy = (q - 1) / 24, qx = (q - 1) % 24;
        int ky = (k - 1) / 24, kx = (k - 1) % 24;
        int ry = qy - ky; ry = ry < -1 ? -1 : (ry > 1 ? 1 : ry);
        int rx = qx - kx; rx = rx < -1 ? -1 : (rx > 1 ? 1 : rx);
        id = (ry + 1) * 3 + (rx + 1);
      }
      v = table[id] * 1.4426950408889634f;
    }
    o8[j] = f2bf(v);
  }
  *(uint4*)(bp + ((size_t)kb * 577 + q) * 8) = *(const uint4*)o8;
}

// bias(q, k=576) * log2e  (k=576 is a regular patch; q=0 is the CLS row)
__global__ void bias576_kernel(const float* __restrict__ table, float* __restrict__ b576) {
  int q = blockIdx.x * 256 + threadIdx.x;
  if (q >= 577) return;
  int id;
  if (q == 0) id = 10;
  else {
    int qy = (q - 1) / 24, qx = (q - 1) % 24;
    int ry = qy - 23; ry = ry < -1 ? -1 : (ry > 1 ? 1 : ry);
    int rx = qx - 23; rx = rx < -1 ? -1 : (rx > 1 ? 1 : rx);
    id = (ry + 1) * 3 + (rx + 1);
  }
  b576[q] = table[id] * 1.4426950408889634f;
}

// ---------------- GEMM (128x128 tile, BK=32, 2-phase dbuf, global_load_lds) ----------------
// T1 bijective XCD swizzle (m204): consecutive logical blocks land on one XCD's L2.

template <int MODE>
__global__ __launch_bounds__(256) void gemm_kernel(
    const u16* __restrict__ A, const u16* __restrict__ BT,
    const int M, const int NBN,
    float* __restrict__ outF, const float* __restrict__ bvec,
    u16* __restrict__ qarr, u16* __restrict__ karr, u16* __restrict__ vTa) {
  constexpr int K = 768;
  __shared__ __align__(16) u16 smem[17408];
  u16* As = smem;
  u16* Bs = smem + 8192;
  u16* Cs = smem;

  // bijective XCD remap
  const int nwg = gridDim.x;
  const int q8 = nwg >> 3, r8 = nwg & 7;
  const int xcd = blockIdx.x & 7, jj = blockIdx.x >> 3;
  const int bid = ((xcd < r8) ? xcd * (q8 + 1) : r8 * (q8 + 1) + (xcd - r8) * q8) + jj;

  const int nb = bid % NBN, mb = bid / NBN;
  const int tid = threadIdx.x;
  const int w = tid >> 6, l = tid & 63;
  const int wr = w >> 1, wc = w & 1;
  const int l15 = l & 15, l4 = l >> 4;
  const int m0 = mb * 128, n0 = nb * 128;

  floatx4 acc[4][4];
#pragma unroll
  for (int i = 0; i < 4; ++i)
#pragma unroll
    for (int j = 0; j < 4; ++j) acc[i][j] = 0.f;

  const int trow = tid >> 2;
  const int tk = (tid & 3) * 8;

  auto stage = [&](int buf, int kt) {
    const int k0 = kt * 32;
#pragma unroll
    for (int i = 0; i < 2; ++i) {
      int row = i * 64 + trow;
      int ar = m0 + row; if (ar >= M) ar = M - 1;
      gload16(A + (size_t)ar * K + k0 + tk, &As[buf * 4096 + row * 32 + tk]);
      int br = n0 + row;
      gload16(BT + (size_t)br * K + k0 + tk, &Bs[buf * 4096 + row * 32 + tk]);
    }
  };

  stage(0, 0);
  __syncthreads();
  int cur = 0;
  for (int kt = 0; kt < 24; ++kt) {
    if (kt + 1 < 24) stage(cur ^ 1, kt + 1);
    short8 af[4], bf[4];
#pragma unroll
    for (int mi = 0; mi < 4; ++mi)
      af[mi] = *(const short8*)&As[cur * 4096 + (wr * 64 + mi * 16 + l15) * 32 + l4 * 8];
#pragma unroll
    for (int ni = 0; ni < 4; ++ni)
      bf[ni] = *(const short8*)&Bs[cur * 4096 + (wc * 64 + ni * 16 + l15) * 32 + l4 * 8];
#pragma unroll
    for (int mi = 0; mi < 4; ++mi)
#pragma unroll
      for (int ni = 0; ni < 4; ++ni)
        acc[mi][ni] = MFMA16(af[mi], bf[ni], acc[mi][ni]);
    __syncthreads();
    cur ^= 1;
  }

  if constexpr (MODE == 0) {
    const int proj = nb / 6;            // 0=q 1=k 2=v
    const int h0 = (nb - proj * 6) * 2;
    const float qs = (proj == 0) ? 0.18033688011112042f : 1.0f;
#pragma unroll
    for (int mi = 0; mi < 4; ++mi)
#pragma unroll
      for (int i = 0; i < 4; ++i) {
        const int rloc = wr * 64 + mi * 16 + l4 * 4 + i;
#pragma unroll
        for (int ni = 0; ni < 4; ++ni) {
          const int cloc = wc * 64 + ni * 16 + l15;
          Cs[rloc * 136 + cloc] = f2bf(acc[mi][ni][i] * qs);
        }
      }
    __syncthreads();

    if (proj < 2) {
      u16* dst = (proj == 0) ? qarr : karr;
      const int r = tid >> 1, half = tid & 1;
      const int mrow = m0 + r;
      if (mrow < M) {
        const int bq = mrow / 577, sq = mrow - bq * 577;
        u16* base = dst + ((size_t)(bq * 12 + h0 + half) * 577 + sq) * 64;
        const u16* src = Cs + r * 136 + half * 64;
#pragma unroll
        for (int j = 0; j < 8; ++j)
          *(uint4*)(base + j * 8) = *(const uint4*)(src + j * 8);
      }
    } else {
      const int rr = tid & 127, chalf = tid >> 7;
      const int mrow = m0 + rr;
      if (mrow < M) {
        const int bq = mrow / 577, sq = mrow - bq * 577;
        u16* vbase = vTa + ((size_t)(bq * 12 + h0 + chalf) * 64) * 608 + sq;
        const u16* src = Cs + rr * 136 + chalf * 64;
#pragma unroll
        for (int dc = 0; dc < 8; ++dc) {
          const short8 vv = *(const short8*)(src + dc * 8);
#pragma unroll
          for (int jjx = 0; jjx < 8; ++jjx)
            vbase[(size_t)(dc * 8 + jjx) * 608] = (u16)vv[jjx];
        }
      }
    }
  } else {
#pragma unroll
    for (int mi = 0; mi < 4; ++mi) {
#pragma unroll
      for (int i = 0; i < 4; ++i) {
        const int mrow = m0 + wr * 64 + mi * 16 + l4 * 4 + i;
        if (mrow >= M) continue;
#pragma unroll
        for (int ni = 0; ni < 4; ++ni) {
          const int ncol = n0 + wc * 64 + ni * 16 + l15;
          outF[(size_t)mrow * 768 + ncol] = acc[mi][ni][i] + bvec[ncol];
        }
      }
    }
  }
}

// ---------------- fused flash attention (KVBLK=64, LDS-staged K/V, swapped QK^T) ----------
// kv 0..575 in 9 tiles of 64 (no tail masking); kv=576 folded into online-softmax init.
// LDS tiles [64][64] with slot-swizzle s(r)=(r&7)^((2(r>>3))&7) on 16B granules:
// linear gload_lds dest + pre-swizzled global source + swizzled ds_read (involution).

__global__ __launch_bounds__(256, 2) void attn_kernel(
    const u16* __restrict__ qg, const u16* __restrict__ kg,
    const u16* __restrict__ vT, const u16* __restrict__ bp,
    const float* __restrict__ b576, u16* __restrict__ xa) {
  const int bid = (blockIdx.x & 7) * 240 + (blockIdx.x >> 3);
  const int bh = bid / 5, qblk = bid - bh * 5;
  const int tid = threadIdx.x;
  const int w = tid >> 6, l = tid & 63;
  const int l15 = l & 15, l4 = l >> 4;
  const int qbase = qblk * 128 + w * 32;

  const u16* qh = qg + (size_t)bh * 577 * 64;
  const u16* kh = kg + (size_t)bh * 577 * 64;
  const u16* vh = vT + (size_t)bh * 64 * 608;

  __shared__ u16 Ks[2][64 * 64];
  __shared__ u16 Vs[2][64 * 64];

  // staging constants: thread stages rows sr and sr+32 (same slot value)
  const int sr = tid >> 3;
  const int sb = tid & 7;
  const int ss = ((sr & 7) ^ ((2 * (sr >> 3)) & 7)) & 7;
  const int scol = (sb ^ ss) * 8;

  // read-side constants
  const int sig = ((l15 >> 2) << 3) + (l15 & 3);
  const int s0_ = ((l15 & 3) ^ ((2 * (l15 >> 2)) & 7)) & 7;
  const int s4_ = s0_ ^ 4;
  const int oK00 = sig * 64 + ((l4 ^ s0_) << 3);
  const int oK01 = sig * 64 + (((l4 + 4) ^ s0_) << 3);
  const int oK10 = (sig + 4) * 64 + ((l4 ^ s4_) << 3);
  const int oK11 = (sig + 4) * 64 + (((l4 + 4) ^ s4_) << 3);
  const int oK20 = oK00 + 32 * 64;
  const int oK21 = oK01 + 32 * 64;
  const int oK30 = oK10 + 32 * 64;
  const int oK31 = oK11 + 32 * 64;
  int oV[4][2];
#pragma unroll
  for (int df = 0; df < 4; ++df) {
    const int r = df * 16 + l15;
    const int sv = ((r & 7) ^ ((2 * (r >> 3)) & 7)) & 7;
    oV[df][0] = r * 64 + ((l4 ^ sv) << 3);
    oV[df][1] = r * 64 + (((l4 + 4) ^ sv) << 3);
  }

  short8 qf[2][2];
  int bq[2];
#pragma unroll
  for (int g = 0; g < 2; ++g) {
    int qr = qbase + g * 16 + l15; if (qr > 576) qr = 576;
    bq[g] = qr;
    qf[g][0] = *(const short8*)(qh + qr * 64 + l4 * 8);
    qf[g][1] = *(const short8*)(qh + qr * 64 + 32 + l4 * 8);
  }

  // ---- init with kv = 576 column ----
  float m[2], lsum[2] = {1.f, 1.f};
  {
    const u16* kp = kh + 576 * 64 + l4 * 8;
    const short8 kA = *(const short8*)(kp);
    const short8 kB = *(const short8*)(kp + 32);
#pragma unroll
    for (int g = 0; g < 2; ++g) {
      float acc = 0.f;
#pragma unroll
      for (int j = 0; j < 8; ++j)
        acc += bf2f((u16)qf[g][0][j]) * bf2f((u16)kA[j]) +
               bf2f((u16)qf[g][1][j]) * bf2f((u16)kB[j]);
      acc += __shfl_xor(acc, 16);
      acc += __shfl_xor(acc, 32);
      m[g] = acc + b576[bq[g]];
    }
  }
  floatx4 o[2][4];
#pragma unroll
  for (int df = 0; df < 4; ++df)
#pragma unroll
    for (int i = 0; i < 4; ++i) {
      const float v5 = bf2f(vh[(size_t)(df * 16 + l4 * 4 + i) * 608 + 576]);
      o[0][df][i] = v5; o[1][df][i] = v5;
    }

  // prologue: stage tile 0
  gload16(kh + (size_t)sr * 64 + scol, &Ks[0][sr * 64 + sb * 8]);
  gload16(kh + (size_t)(sr + 32) * 64 + scol, &Ks[0][(sr + 32) * 64 + sb * 8]);
  gload16(vh + (size_t)sr * 608 + scol, &Vs[0][sr * 64 + sb * 8]);
  gload16(vh + (size_t)(sr + 32) * 608 + scol, &Vs[0][(sr + 32) * 64 + sb * 8]);
  __syncthreads();

  for (int t = 0; t < 9; ++t) {
    const int cur = t & 1;
    if (t < 8) {
      const int nk = (t + 1) * 64;
      gload16(kh + (size_t)(nk + sr) * 64 + scol, &Ks[cur ^ 1][sr * 64 + sb * 8]);
      gload16(kh + (size_t)(nk + sr + 32) * 64 + scol, &Ks[cur ^ 1][(sr + 32) * 64 + sb * 8]);
      gload16(vh + (size_t)sr * 608 + nk + scol, &Vs[cur ^ 1][sr * 64 + sb * 8]);
      gload16(vh + (size_t)(sr + 32) * 608 + nk + scol, &Vs[cur ^ 1][(sr + 32) * 64 + sb * 8]);
    }

    const int kba = t * 8 + l4;
    const uint4 ba0 = *(const uint4*)(bp + ((size_t)kba * 577 + bq[0]) * 8);
    const uint4 bb0 = *(const uint4*)(bp + ((size_t)(kba + 4) * 577 + bq[0]) * 8);
    const uint4 ba1 = *(const uint4*)(bp + ((size_t)kba * 577 + bq[1]) * 8);
    const uint4 bb1 = *(const uint4*)(bp + ((size_t)(kba + 4) * 577 + bq[1]) * 8);

    const u16* kb_ = &Ks[cur][0];
    const short8 K00 = *(const short8*)(kb_ + oK00);
    const short8 K01 = *(const short8*)(kb_ + oK01);
    const short8 K10 = *(const short8*)(kb_ + oK10);
    const short8 K11 = *(const short8*)(kb_ + oK11);
    const short8 K20 = *(const short8*)(kb_ + oK20);
    const short8 K21 = *(const short8*)(kb_ + oK21);
    const short8 K30 = *(const short8*)(kb_ + oK30);
    const short8 K31 = *(const short8*)(kb_ + oK31);

    floatx4 sA0[2], sA1[2], sB0[2], sB1[2];
    __builtin_amdgcn_s_setprio(1);
#pragma unroll
    for (int g = 0; g < 2; ++g) {
      floatx4 a0 = 0.f, a1 = 0.f, b0 = 0.f, b1 = 0.f;
      a0 = MFMA16(K00, qf[g][0], a0); a0 = MFMA16(K01, qf[g][1], a0);
      a1 = MFMA16(K10, qf[g][0], a1); a1 = MFMA16(K11, qf[g][1], a1);
      b0 = MFMA16(K20, qf[g][0], b0); b0 = MFMA16(K21, qf[g][1], b0);
      b1 = MFMA16(K30, qf[g][0], b1); b1 = MFMA16(K31, qf[g][1], b1);
      sA0[g] = a0; sA1[g] = a1; sB0[g] = b0; sB1[g] = b1;
    }
    __builtin_amdgcn_s_setprio(0);

    float v_[2][16];
#pragma unroll
    for (int g = 0; g < 2; ++g) {
      const uint4 ba = (g == 0) ? ba0 : ba1;
      const uint4 bb = (g == 0) ? bb0 : bb1;
      v_[g][0] = sA0[g][0] + bflo(ba.x);  v_[g][1] = sA0[g][1] + bfhi(ba.x);
      v_[g][2] = sA0[g][2] + bflo(ba.y);  v_[g][3] = sA0[g][3] + bfhi(ba.y);
      v_[g][4] = sA1[g][0] + bflo(ba.z);  v_[g][5] = sA1[g][1] + bfhi(ba.z);
      v_[g][6] = sA1[g][2] + bflo(ba.w);  v_[g][7] = sA1[g][3] + bfhi(ba.w);
      v_[g][8]  = sB0[g][0] + bflo(bb.x); v_[g][9]  = sB0[g][1] + bfhi(bb.x);
      v_[g][10] = sB0[g][2] + bflo(bb.y); v_[g][11] = sB0[g][3] + bfhi(bb.y);
      v_[g][12] = sB1[g][0] + bflo(bb.z); v_[g][13] = sB1[g][1] + bfhi(bb.z);
      v_[g][14] = sB1[g][2] + bflo(bb.w); v_[g][15] = sB1[g][3] + bfhi(bb.w);
    }

    float vm[2];
#pragma unroll
    for (int g = 0; g < 2; ++g) {
      float a = v_[g][0];
#pragma unroll
      for (int j = 1; j < 16; ++j) a = fmaxf(a, v_[g][j]);
      a = fmaxf(a, __shfl_xor(a, 16));
      a = fmaxf(a, __shfl_xor(a, 32));
      vm[g] = a;
    }

    if (__any((vm[0] > m[0] + 8.f) || (vm[1] > m[1] + 8.f))) {
      const float mn0 = fmaxf(m[0], vm[0]), mn1 = fmaxf(m[1], vm[1]);
      const float sc0 = exp2hw(m[0] - mn0), sc1 = exp2hw(m[1] - mn1);
      lsum[0] *= sc0; lsum[1] *= sc1;
#pragma unroll
      for (int df = 0; df < 4; ++df) { o[0][df] *= sc0; o[1][df] *= sc1; }
      m[0] = mn0; m[1] = mn1;
    }

    union PU { unsigned u[4]; short8 s; };
    PU pA[2], pB[2];
#pragma unroll
    for (int g = 0; g < 2; ++g) {
      float rs = 0.f;
#pragma unroll
      for (int j = 0; j < 16; ++j) { v_[g][j] = exp2hw(v_[g][j] - m[g]); rs += v_[g][j]; }
      rs += __shfl_xor(rs, 16);
      rs += __shfl_xor(rs, 32);
      lsum[g] += rs;
#pragma unroll
      for (int j = 0; j < 4; ++j) {
        pA[g].u[j] = cvtpk_bf16(v_[g][2 * j], v_[g][2 * j + 1]);
        pB[g].u[j] = cvtpk_bf16(v_[g][8 + 2 * j], v_[g][8 + 2 * j + 1]);
      }
    }

    const u16* vb_ = &Vs[cur][0];
    const short8 vA0 = *(const short8*)(vb_ + oV[0][0]);
    const short8 vB0 = *(const short8*)(vb_ + oV[0][1]);
    const short8 vA1 = *(const short8*)(vb_ + oV[1][0]);
    const short8 vB1 = *(const short8*)(vb_ + oV[1][1]);
    const short8 vA2 = *(const short8*)(vb_ + oV[2][0]);
    const short8 vB2 = *(const short8*)(vb_ + oV[2][1]);
    const short8 vA3 = *(const short8*)(vb_ + oV[3][0]);
    const short8 vB3 = *(const short8*)(vb_ + oV[3][1]);

    __builtin_amdgcn_s_setprio(1);
#pragma unroll
    for (int g = 0; g < 2; ++g) {
      o[g][0] = MFMA16(vA0, pA[g].s, o[g][0]); o[g][0] = MFMA16(vB0, pB[g].s, o[g][0]);
      o[g][1] = MFMA16(vA1, pA[g].s, o[g][1]); o[g][1] = MFMA16(vB1, pB[g].s, o[g][1]);
      o[g][2] = MFMA16(vA2, pA[g].s, o[g][2]); o[g][2] = MFMA16(vB2, pB[g].s, o[g][2]);
      o[g][3] = MFMA16(vA3, pA[g].s, o[g][3]); o[g][3] = MFMA16(vB3, pB[g].s, o[g][3]);
    }
    __builtin_amdgcn_s_setprio(0);

    __syncthreads();
  }

  const int b = bh / 12, h = bh - (bh / 12) * 12;
#pragma unroll
  for (int g = 0; g < 2; ++g) {
    const int gq = qbase + g * 16 + l15;
    if (gq < 577) {
      const float inv = 1.f / lsum[g];
      u16* op = xa + ((size_t)(b * 577 + gq)) * 768 + h * 64 + l4 * 4;
#pragma unroll
      for (int d = 0; d < 4; ++d) {
        unsigned w0 = cvtpk_bf16(o[g][d][0] * inv, o[g][d][1] * inv);
        unsigned w1 = cvtpk_bf16(o[g][d][2] * inv, o[g][d][3] * inv);
        *(unsigned*)(op + d * 16) = w0;
        *(unsigned*)(op + d * 16 + 2) = w1;
      }
    }
  }
}

// ---------------- launch ----------------

extern "C" void kernel_launch(void* const* d_in, const int* in_sizes, int n_in,
                              void* d_out, int out_size, void* d_ws, size_t ws_size,
                              hipStream_t stream) {
  const float* x  = (const float*)d_in[0];
  const float* Wq = (const float*)d_in[1];
  const float* Wk = (const float*)d_in[2];
  const float* Wv = (const float*)d_in[3];
  const float* Wo = (const float*)d_in[4];
  const float* bo = (const float*)d_in[5];
  const float* bt = (const float*)d_in[6];
  float* out = (float*)d_out;

  char* ws = (char*)d_ws;
  size_t off = 0;
  auto alloc = [&](size_t bytes) {
    void* p = ws + off;
    off += (bytes + 255) & ~(size_t)255;
    return p;
  };
  u16* xb   = (u16*)alloc((size_t)18464 * 768 * 2);   // reused as xa after GEMM0
  u16* WT   = (u16*)alloc((size_t)2304 * 768 * 2);
  u16* WoT  = (u16*)alloc((size_t)768 * 768 * 2);
  u16* qa   = (u16*)alloc((size_t)384 * 577 * 64 * 2);
  u16* ka   = (u16*)alloc((size_t)384 * 577 * 64 * 2);
  u16* vT   = (u16*)alloc((size_t)384 * 64 * 608 * 2);
  u16* biasPk = (u16*)alloc((size_t)76 * 577 * 8 * 2);
  float* b576 = (float*)alloc((size_t)577 * 4);
  (void)ws_size; (void)in_sizes; (void)n_in; (void)out_size;

  cvt_x_kernel<<<(18464 * 768 / 4 + 255) / 256, 256, 0, stream>>>(x, xb, 18464 * 768 / 4);
  dim3 tg(12, 12);
  cvt_wT_kernel<<<tg, 256, 0, stream>>>(Wq, WT);
  cvt_wT_kernel<<<tg, 256, 0, stream>>>(Wk, WT + (size_t)768 * 768);
  cvt_wT_kernel<<<tg, 256, 0, stream>>>(Wv, WT + (size_t)2 * 768 * 768);
  cvt_wT_kernel<<<tg, 256, 0, stream>>>(Wo, WoT);
  bias_kernel<<<(577 * 76 + 255) / 256, 256, 0, stream>>>(bt, biasPk);
  bias576_kernel<<<3, 256, 0, stream>>>(bt, b576);

  // QKV projection: writes q,k row-major and v directly transposed into vT
  gemm_kernel<0><<<145 * 18, 256, 0, stream>>>(xb, WT, 18464, 18,
                                               nullptr, nullptr, qa, ka, vT);
  // attention -> xa (reuse xb region)
  attn_kernel<<<1920, 256, 0, stream>>>(qa, ka, vT, biasPk, b576, xb);
  // output projection: xa x WoT + bo -> out (f32)
  gemm_kernel<1><<<145 * 6, 256, 0, stream>>>(xb, WoT, 18464, 6,
                                              out, bo, nullptr, nullptr, nullptr);
}

// Round 8
// 233.164 us; speedup vs baseline: 1.9375x; 1.0617x over previous
//
#include <hip/hip_runtime.h>

typedef unsigned short u16;
typedef short short8 __attribute__((ext_vector_type(8)));
typedef float floatx4 __attribute__((ext_vector_type(4)));

#define MFMA16(a, b, c) __builtin_amdgcn_mfma_f32_16x16x32_bf16((a), (b), (c), 0, 0, 0)

__device__ __forceinline__ u16 f2bf(float f) {
  unsigned u = __builtin_bit_cast(unsigned, f);
  u = (u + 0x7fffu + ((u >> 16) & 1u)) >> 16;
  return (u16)u;
}

__device__ __forceinline__ float bf2f(u16 u) {
  return __builtin_bit_cast(float, ((unsigned)u) << 16);
}

__device__ __forceinline__ float exp2hw(float x) {
  float r; asm("v_exp_f32 %0, %1" : "=v"(r) : "v"(x)); return r;
}

__device__ __forceinline__ unsigned cvtpk_bf16(float lo, float hi) {
  unsigned r;
  asm("v_cvt_pk_bf16_f32 %0, %1, %2" : "=v"(r) : "v"(lo), "v"(hi));
  return r;
}

__device__ __forceinline__ float bflo(unsigned u) {
  return __builtin_bit_cast(float, u << 16);
}
__device__ __forceinline__ float bfhi(unsigned u) {
  return __builtin_bit_cast(float, u & 0xffff0000u);
}

__device__ __forceinline__ void gload16(const void* g, void* l) {
  typedef __attribute__((address_space(1))) const void GV;
  typedef __attribute__((address_space(3))) void LV;
  __builtin_amdgcn_global_load_lds((GV*)g, (LV*)l, 16, 0, 0);
}

// ---------------- convert / prep kernels ----------------

__global__ void cvt_x_kernel(const float* __restrict__ x, u16* __restrict__ xb, int n4) {
  int i = blockIdx.x * 256 + threadIdx.x;
  if (i >= n4) return;
  float4 v = ((const float4*)x)[i];
  ushort4 r; r.x = f2bf(v.x); r.y = f2bf(v.y); r.z = f2bf(v.z); r.w = f2bf(v.w);
  ((ushort4*)xb)[i] = r;
}

// out[n][k] = bf16(in[k][n]), in is [768][768] f32 row-major
__global__ void cvt_wT_kernel(const float* __restrict__ in, u16* __restrict__ out) {
  __shared__ float tile[64][65];
  const int k0 = blockIdx.x * 64, n0 = blockIdx.y * 64;
  const int t = threadIdx.x;
  const int tr = t >> 6, tc = t & 63;
#pragma unroll
  for (int i = 0; i < 16; ++i) {
    int row = i * 4 + tr;
    tile[row][tc] = in[(size_t)(k0 + row) * 768 + n0 + tc];
  }
  __syncthreads();
#pragma unroll
  for (int i = 0; i < 16; ++i) {
    int row = i * 4 + tr;
    out[(size_t)(n0 + row) * 768 + k0 + tc] = f2bf(tile[tc][row]);
  }
}

// bias in bf16 fragment layout: bp[(kb*577 + q)*8 + j] = log2e * bias(q, k=kb*8+j)
__global__ void bias_kernel(const float* __restrict__ table, u16* __restrict__ bp) {
  int idx = blockIdx.x * 256 + threadIdx.x;
  if (idx >= 577 * 76) return;
  int q = idx / 76, kb = idx - q * 76;
  u16 o8[8];
#pragma unroll
  for (int j = 0; j < 8; ++j) {
    int k = kb * 8 + j;
    float v = 0.f;
    if (k <= 576) {
      int id;
      if (q == 0 && k == 0) id = 9;
      else if (q == 0) id = 10;
      else if (k == 0) id = 11;
      else {
        int qy = (q - 1) / 24, qx = (q - 1) % 24;
        int ky = (k - 1) / 24, kx = (k - 1) % 24;
        int ry = qy - ky; ry = ry < -1 ? -1 : (ry > 1 ? 1 : ry);
        int rx = qx - kx; rx = rx < -1 ? -1 : (rx > 1 ? 1 : rx);
        id = (ry + 1) * 3 + (rx + 1);
      }
      v = table[id] * 1.4426950408889634f;
    }
    o8[j] = f2bf(v);
  }
  *(uint4*)(bp + ((size_t)kb * 577 + q) * 8) = *(const uint4*)o8;
}

// bias(q, k=576) * log2e
__global__ void bias576_kernel(const float* __restrict__ table, float* __restrict__ b576) {
  int q = blockIdx.x * 256 + threadIdx.x;
  if (q >= 577) return;
  int id;
  if (q == 0) id = 10;
  else {
    int qy = (q - 1) / 24, qx = (q - 1) % 24;
    int ry = qy - 23; ry = ry < -1 ? -1 : (ry > 1 ? 1 : ry);
    int rx = qx - 23; rx = rx < -1 ? -1 : (rx > 1 ? 1 : rx);
    id = (ry + 1) * 3 + (rx + 1);
  }
  b576[q] = table[id] * 1.4426950408889634f;
}

// ---------------- GEMM (256x256 tile, BK=32, 2-phase dbuf, global_load_lds) ----------------
// 512 threads = 8 waves (2M x 4N); per-wave output 128x64; acc[8][4].
// MODE 0: QKV epilogue via 2-pass LDS bounce (q/k row-major 16B stores; v transposed
// into vT with lane-consecutive sq). MODE 1: direct f32 + bias.

template <int MODE>
__global__ __launch_bounds__(512, 2) void gemm_kernel(
    const u16* __restrict__ A, const u16* __restrict__ BT,
    const int M, const int NBN,
    float* __restrict__ outF, const float* __restrict__ bvec,
    u16* __restrict__ qarr, u16* __restrict__ karr, u16* __restrict__ vTa) {
  constexpr int K = 768;
  // staging: As[2][8192] + Bs[2][8192] u16 = 64 KB; epilogue bounce Cs[128][264] = 66 KB
  __shared__ __align__(16) u16 smem[33792];
  u16* As = smem;           // [2][8192]
  u16* Bs = smem + 16384;   // [2][8192]
  u16* Cs = smem;

  // bijective XCD remap (m204)
  const int nwg = gridDim.x;
  const int q8 = nwg >> 3, r8 = nwg & 7;
  const int xcd = blockIdx.x & 7, jj = blockIdx.x >> 3;
  const int bid = ((xcd < r8) ? xcd * (q8 + 1) : r8 * (q8 + 1) + (xcd - r8) * q8) + jj;

  const int nb = bid % NBN, mb = bid / NBN;
  const int tid = threadIdx.x;
  const int wid = tid >> 6, l = tid & 63;
  const int wrm = wid >> 2, wcn = wid & 3;
  const int l15 = l & 15, l4 = l >> 4;
  const int m0 = mb * 256, n0 = nb * 256;

  floatx4 acc[8][4];
#pragma unroll
  for (int i = 0; i < 8; ++i)
#pragma unroll
    for (int j = 0; j < 4; ++j) acc[i][j] = 0.f;

  const int r1 = tid >> 2;          // 0..127
  const int g1 = (tid & 3) * 8;     // col elem offset

  auto stage = [&](int buf, int kt) {
    const int k0 = kt * 32 + g1;
    int ar0 = m0 + r1;       if (ar0 >= M) ar0 = M - 1;
    int ar1 = m0 + r1 + 128; if (ar1 >= M) ar1 = M - 1;
    gload16(A + (size_t)ar0 * K + k0, &As[buf * 8192 + tid * 8]);
    gload16(A + (size_t)ar1 * K + k0, &As[buf * 8192 + 4096 + tid * 8]);
    gload16(BT + (size_t)(n0 + r1) * K + k0, &Bs[buf * 8192 + tid * 8]);
    gload16(BT + (size_t)(n0 + r1 + 128) * K + k0, &Bs[buf * 8192 + 4096 + tid * 8]);
  };

  stage(0, 0);
  __syncthreads();
  int cur = 0;
  for (int kt = 0; kt < 24; ++kt) {
    if (kt + 1 < 24) stage(cur ^ 1, kt + 1);
    short8 af[8], bf[4];
#pragma unroll
    for (int mi = 0; mi < 8; ++mi)
      af[mi] = *(const short8*)&As[cur * 8192 + (wrm * 128 + mi * 16 + l15) * 32 + l4 * 8];
#pragma unroll
    for (int ni = 0; ni < 4; ++ni)
      bf[ni] = *(const short8*)&Bs[cur * 8192 + (wcn * 64 + ni * 16 + l15) * 32 + l4 * 8];
#pragma unroll
    for (int mi = 0; mi < 8; ++mi)
#pragma unroll
      for (int ni = 0; ni < 4; ++ni)
        acc[mi][ni] = MFMA16(af[mi], bf[ni], acc[mi][ni]);
    __syncthreads();
    cur ^= 1;
  }

  if constexpr (MODE == 0) {
    const int proj = nb / 3;              // 0=q 1=k 2=v (256 cols = 4 heads)
    const int h0 = (nb - proj * 3) * 4;
    const float qs = (proj == 0) ? 0.18033688011112042f : 1.0f;
#pragma unroll
    for (int p = 0; p < 2; ++p) {
      __syncthreads();
      if (wrm == p) {
#pragma unroll
        for (int mi = 0; mi < 8; ++mi)
#pragma unroll
          for (int i = 0; i < 4; ++i) {
            const int rloc = mi * 16 + l4 * 4 + i;
#pragma unroll
            for (int ni = 0; ni < 4; ++ni)
              Cs[rloc * 264 + wcn * 64 + ni * 16 + l15] = f2bf(acc[mi][ni][i] * qs);
          }
      }
      __syncthreads();
      const int r = tid & 127, ch = tid >> 7;   // 128 rows x 4 head-chunks
      const int mrow = m0 + p * 128 + r;
      if (mrow < M) {
        const int bq = mrow / 577, sq = mrow - bq * 577;
        const u16* src = Cs + r * 264 + ch * 64;
        if (proj < 2) {
          u16* dst = (proj == 0) ? qarr : karr;
          u16* base = dst + ((size_t)(bq * 12 + h0 + ch) * 577 + sq) * 64;
#pragma unroll
          for (int j2 = 0; j2 < 8; ++j2)
            *(uint4*)(base + j2 * 8) = *(const uint4*)(src + j2 * 8);
        } else {
          u16* vbase = vTa + ((size_t)(bq * 12 + h0 + ch) * 64) * 608 + sq;
#pragma unroll
          for (int dc = 0; dc < 8; ++dc) {
            const short8 vv = *(const short8*)(src + dc * 8);
#pragma unroll
            for (int jx = 0; jx < 8; ++jx)
              vbase[(size_t)(dc * 8 + jx) * 608] = (u16)vv[jx];
          }
        }
      }
    }
  } else {
#pragma unroll
    for (int mi = 0; mi < 8; ++mi) {
#pragma unroll
      for (int i = 0; i < 4; ++i) {
        const int mrow = m0 + wrm * 128 + mi * 16 + l4 * 4 + i;
        if (mrow >= M) continue;
#pragma unroll
        for (int ni = 0; ni < 4; ++ni) {
          const int ncol = n0 + wcn * 64 + ni * 16 + l15;
          outF[(size_t)mrow * 768 + ncol] = acc[mi][ni][i] + bvec[ncol];
        }
      }
    }
  }
}

// ---------------- fused flash attention (KVBLK=64, LDS-staged K/V, swapped QK^T) ----------
// kv 0..575 in 9 tiles of 64; kv=576 folded into the online-softmax init.
// Bias fragments double-buffered one tile ahead (off the critical path).

__global__ __launch_bounds__(256, 2) void attn_kernel(
    const u16* __restrict__ qg, const u16* __restrict__ kg,
    const u16* __restrict__ vT, const u16* __restrict__ bp,
    const float* __restrict__ b576, u16* __restrict__ xa) {
  const int bid = (blockIdx.x & 7) * 240 + (blockIdx.x >> 3);
  const int bh = bid / 5, qblk = bid - bh * 5;
  const int tid = threadIdx.x;
  const int w = tid >> 6, l = tid & 63;
  const int l15 = l & 15, l4 = l >> 4;
  const int qbase = qblk * 128 + w * 32;

  const u16* qh = qg + (size_t)bh * 577 * 64;
  const u16* kh = kg + (size_t)bh * 577 * 64;
  const u16* vh = vT + (size_t)bh * 64 * 608;

  __shared__ u16 Ks[2][64 * 64];
  __shared__ u16 Vs[2][64 * 64];

  // staging constants
  const int sr = tid >> 3;
  const int sb = tid & 7;
  const int ss = ((sr & 7) ^ ((2 * (sr >> 3)) & 7)) & 7;
  const int scol = (sb ^ ss) * 8;

  // read-side constants
  const int sig = ((l15 >> 2) << 3) + (l15 & 3);
  const int s0_ = ((l15 & 3) ^ ((2 * (l15 >> 2)) & 7)) & 7;
  const int s4_ = s0_ ^ 4;
  const int oK00 = sig * 64 + ((l4 ^ s0_) << 3);
  const int oK01 = sig * 64 + (((l4 + 4) ^ s0_) << 3);
  const int oK10 = (sig + 4) * 64 + ((l4 ^ s4_) << 3);
  const int oK11 = (sig + 4) * 64 + (((l4 + 4) ^ s4_) << 3);
  const int oK20 = oK00 + 32 * 64;
  const int oK21 = oK01 + 32 * 64;
  const int oK30 = oK10 + 32 * 64;
  const int oK31 = oK11 + 32 * 64;
  int oV[4][2];
#pragma unroll
  for (int df = 0; df < 4; ++df) {
    const int r = df * 16 + l15;
    const int sv = ((r & 7) ^ ((2 * (r >> 3)) & 7)) & 7;
    oV[df][0] = r * 64 + ((l4 ^ sv) << 3);
    oV[df][1] = r * 64 + (((l4 + 4) ^ sv) << 3);
  }

  short8 qf[2][2];
  int bq[2];
#pragma unroll
  for (int g = 0; g < 2; ++g) {
    int qr = qbase + g * 16 + l15; if (qr > 576) qr = 576;
    bq[g] = qr;
    qf[g][0] = *(const short8*)(qh + qr * 64 + l4 * 8);
    qf[g][1] = *(const short8*)(qh + qr * 64 + 32 + l4 * 8);
  }

  // ---- init with kv = 576 column ----
  float m[2], lsum[2] = {1.f, 1.f};
  {
    const u16* kp = kh + 576 * 64 + l4 * 8;
    const short8 kA = *(const short8*)(kp);
    const short8 kB = *(const short8*)(kp + 32);
#pragma unroll
    for (int g = 0; g < 2; ++g) {
      float acc = 0.f;
#pragma unroll
      for (int j = 0; j < 8; ++j)
        acc += bf2f((u16)qf[g][0][j]) * bf2f((u16)kA[j]) +
               bf2f((u16)qf[g][1][j]) * bf2f((u16)kB[j]);
      acc += __shfl_xor(acc, 16);
      acc += __shfl_xor(acc, 32);
      m[g] = acc + b576[bq[g]];
    }
  }
  floatx4 o[2][4];
#pragma unroll
  for (int df = 0; df < 4; ++df)
#pragma unroll
    for (int i = 0; i < 4; ++i) {
      const float v5 = bf2f(vh[(size_t)(df * 16 + l4 * 4 + i) * 608 + 576]);
      o[0][df][i] = v5; o[1][df][i] = v5;
    }

  // prologue: stage tile 0, prefetch tile-0 bias
  gload16(kh + (size_t)sr * 64 + scol, &Ks[0][sr * 64 + sb * 8]);
  gload16(kh + (size_t)(sr + 32) * 64 + scol, &Ks[0][(sr + 32) * 64 + sb * 8]);
  gload16(vh + (size_t)sr * 608 + scol, &Vs[0][sr * 64 + sb * 8]);
  gload16(vh + (size_t)(sr + 32) * 608 + scol, &Vs[0][(sr + 32) * 64 + sb * 8]);
  uint4 bcA0 = *(const uint4*)(bp + ((size_t)l4 * 577 + bq[0]) * 8);
  uint4 bcB0 = *(const uint4*)(bp + ((size_t)(l4 + 4) * 577 + bq[0]) * 8);
  uint4 bcA1 = *(const uint4*)(bp + ((size_t)l4 * 577 + bq[1]) * 8);
  uint4 bcB1 = *(const uint4*)(bp + ((size_t)(l4 + 4) * 577 + bq[1]) * 8);
  __syncthreads();

  for (int t = 0; t < 9; ++t) {
    const int cur = t & 1;
    uint4 nA0 = bcA0, nB0 = bcB0, nA1 = bcA1, nB1 = bcB1;
    if (t < 8) {
      const int nk = (t + 1) * 64;
      gload16(kh + (size_t)(nk + sr) * 64 + scol, &Ks[cur ^ 1][sr * 64 + sb * 8]);
      gload16(kh + (size_t)(nk + sr + 32) * 64 + scol, &Ks[cur ^ 1][(sr + 32) * 64 + sb * 8]);
      gload16(vh + (size_t)sr * 608 + nk + scol, &Vs[cur ^ 1][sr * 64 + sb * 8]);
      gload16(vh + (size_t)(sr + 32) * 608 + nk + scol, &Vs[cur ^ 1][(sr + 32) * 64 + sb * 8]);
      const int kba = (t + 1) * 8 + l4;
      nA0 = *(const uint4*)(bp + ((size_t)kba * 577 + bq[0]) * 8);
      nB0 = *(const uint4*)(bp + ((size_t)(kba + 4) * 577 + bq[0]) * 8);
      nA1 = *(const uint4*)(bp + ((size_t)kba * 577 + bq[1]) * 8);
      nB1 = *(const uint4*)(bp + ((size_t)(kba + 4) * 577 + bq[1]) * 8);
    }

    const u16* kb_ = &Ks[cur][0];
    const short8 K00 = *(const short8*)(kb_ + oK00);
    const short8 K01 = *(const short8*)(kb_ + oK01);
    const short8 K10 = *(const short8*)(kb_ + oK10);
    const short8 K11 = *(const short8*)(kb_ + oK11);
    const short8 K20 = *(const short8*)(kb_ + oK20);
    const short8 K21 = *(const short8*)(kb_ + oK21);
    const short8 K30 = *(const short8*)(kb_ + oK30);
    const short8 K31 = *(const short8*)(kb_ + oK31);

    floatx4 sA0[2], sA1[2], sB0[2], sB1[2];
    __builtin_amdgcn_s_setprio(1);
#pragma unroll
    for (int g = 0; g < 2; ++g) {
      floatx4 a0 = 0.f, a1 = 0.f, b0 = 0.f, b1 = 0.f;
      a0 = MFMA16(K00, qf[g][0], a0); a0 = MFMA16(K01, qf[g][1], a0);
      a1 = MFMA16(K10, qf[g][0], a1); a1 = MFMA16(K11, qf[g][1], a1);
      b0 = MFMA16(K20, qf[g][0], b0); b0 = MFMA16(K21, qf[g][1], b0);
      b1 = MFMA16(K30, qf[g][0], b1); b1 = MFMA16(K31, qf[g][1], b1);
      sA0[g] = a0; sA1[g] = a1; sB0[g] = b0; sB1[g] = b1;
    }
    __builtin_amdgcn_s_setprio(0);

    float v_[2][16];
#pragma unroll
    for (int g = 0; g < 2; ++g) {
      const uint4 ba = (g == 0) ? bcA0 : bcA1;
      const uint4 bb = (g == 0) ? bcB0 : bcB1;
      v_[g][0] = sA0[g][0] + bflo(ba.x);  v_[g][1] = sA0[g][1] + bfhi(ba.x);
      v_[g][2] = sA0[g][2] + bflo(ba.y);  v_[g][3] = sA0[g][3] + bfhi(ba.y);
      v_[g][4] = sA1[g][0] + bflo(ba.z);  v_[g][5] = sA1[g][1] + bfhi(ba.z);
      v_[g][6] = sA1[g][2] + bflo(ba.w);  v_[g][7] = sA1[g][3] + bfhi(ba.w);
      v_[g][8]  = sB0[g][0] + bflo(bb.x); v_[g][9]  = sB0[g][1] + bfhi(bb.x);
      v_[g][10] = sB0[g][2] + bflo(bb.y); v_[g][11] = sB0[g][3] + bfhi(bb.y);
      v_[g][12] = sB1[g][0] + bflo(bb.z); v_[g][13] = sB1[g][1] + bfhi(bb.z);
      v_[g][14] = sB1[g][2] + bflo(bb.w); v_[g][15] = sB1[g][3] + bfhi(bb.w);
    }

    // tree max (depth 4)
    float vm[2];
#pragma unroll
    for (int g = 0; g < 2; ++g) {
      float m0_ = fmaxf(v_[g][0], v_[g][1]),  m1_ = fmaxf(v_[g][2], v_[g][3]);
      float m2_ = fmaxf(v_[g][4], v_[g][5]),  m3_ = fmaxf(v_[g][6], v_[g][7]);
      float m4_ = fmaxf(v_[g][8], v_[g][9]),  m5_ = fmaxf(v_[g][10], v_[g][11]);
      float m6_ = fmaxf(v_[g][12], v_[g][13]), m7_ = fmaxf(v_[g][14], v_[g][15]);
      float a = fmaxf(fmaxf(m0_, m1_), fmaxf(m2_, m3_));
      float b = fmaxf(fmaxf(m4_, m5_), fmaxf(m6_, m7_));
      a = fmaxf(a, b);
      a = fmaxf(a, __shfl_xor(a, 16));
      a = fmaxf(a, __shfl_xor(a, 32));
      vm[g] = a;
    }

    if (__any((vm[0] > m[0] + 8.f) || (vm[1] > m[1] + 8.f))) {
      const float mn0 = fmaxf(m[0], vm[0]), mn1 = fmaxf(m[1], vm[1]);
      const float sc0 = exp2hw(m[0] - mn0), sc1 = exp2hw(m[1] - mn1);
      lsum[0] *= sc0; lsum[1] *= sc1;
#pragma unroll
      for (int df = 0; df < 4; ++df) { o[0][df] *= sc0; o[1][df] *= sc1; }
      m[0] = mn0; m[1] = mn1;
    }

    union PU { unsigned u[4]; short8 s; };
    PU pA[2], pB[2];
#pragma unroll
    for (int g = 0; g < 2; ++g) {
#pragma unroll
      for (int j = 0; j < 16; ++j) v_[g][j] = exp2hw(v_[g][j] - m[g]);
      // tree sum (depth 4)
      float s0 = (v_[g][0] + v_[g][1]) + (v_[g][2] + v_[g][3]);
      float s1 = (v_[g][4] + v_[g][5]) + (v_[g][6] + v_[g][7]);
      float s2 = (v_[g][8] + v_[g][9]) + (v_[g][10] + v_[g][11]);
      float s3 = (v_[g][12] + v_[g][13]) + (v_[g][14] + v_[g][15]);
      float rs = (s0 + s1) + (s2 + s3);
      rs += __shfl_xor(rs, 16);
      rs += __shfl_xor(rs, 32);
      lsum[g] += rs;
#pragma unroll
      for (int j = 0; j < 4; ++j) {
        pA[g].u[j] = cvtpk_bf16(v_[g][2 * j], v_[g][2 * j + 1]);
        pB[g].u[j] = cvtpk_bf16(v_[g][8 + 2 * j], v_[g][8 + 2 * j + 1]);
      }
    }

    const u16* vb_ = &Vs[cur][0];
    const short8 vA0 = *(const short8*)(vb_ + oV[0][0]);
    const short8 vB0 = *(const short8*)(vb_ + oV[0][1]);
    const short8 vA1 = *(const short8*)(vb_ + oV[1][0]);
    const short8 vB1 = *(const short8*)(vb_ + oV[1][1]);
    const short8 vA2 = *(const short8*)(vb_ + oV[2][0]);
    const short8 vB2 = *(const short8*)(vb_ + oV[2][1]);
    const short8 vA3 = *(const short8*)(vb_ + oV[3][0]);
    const short8 vB3 = *(const short8*)(vb_ + oV[3][1]);

    __builtin_amdgcn_s_setprio(1);
#pragma unroll
    for (int g = 0; g < 2; ++g) {
      o[g][0] = MFMA16(vA0, pA[g].s, o[g][0]); o[g][0] = MFMA16(vB0, pB[g].s, o[g][0]);
      o[g][1] = MFMA16(vA1, pA[g].s, o[g][1]); o[g][1] = MFMA16(vB1, pB[g].s, o[g][1]);
      o[g][2] = MFMA16(vA2, pA[g].s, o[g][2]); o[g][2] = MFMA16(vB2, pB[g].s, o[g][2]);
      o[g][3] = MFMA16(vA3, pA[g].s, o[g][3]); o[g][3] = MFMA16(vB3, pB[g].s, o[g][3]);
    }
    __builtin_amdgcn_s_setprio(0);

    bcA0 = nA0; bcB0 = nB0; bcA1 = nA1; bcB1 = nB1;
    __syncthreads();
  }

  const int b = bh / 12, h = bh - (bh / 12) * 12;
#pragma unroll
  for (int g = 0; g < 2; ++g) {
    const int gq = qbase + g * 16 + l15;
    if (gq < 577) {
      const float inv = 1.f / lsum[g];
      u16* op = xa + ((size_t)(b * 577 + gq)) * 768 + h * 64 + l4 * 4;
#pragma unroll
      for (int d = 0; d < 4; ++d) {
        unsigned w0 = cvtpk_bf16(o[g][d][0] * inv, o[g][d][1] * inv);
        unsigned w1 = cvtpk_bf16(o[g][d][2] * inv, o[g][d][3] * inv);
        *(unsigned*)(op + d * 16) = w0;
        *(unsigned*)(op + d * 16 + 2) = w1;
      }
    }
  }
}

// ---------------- launch ----------------

extern "C" void kernel_launch(void* const* d_in, const int* in_sizes, int n_in,
                              void* d_out, int out_size, void* d_ws, size_t ws_size,
                              hipStream_t stream) {
  const float* x  = (const float*)d_in[0];
  const float* Wq = (const float*)d_in[1];
  const float* Wk = (const float*)d_in[2];
  const float* Wv = (const float*)d_in[3];
  const float* Wo = (const float*)d_in[4];
  const float* bo = (const float*)d_in[5];
  const float* bt = (const float*)d_in[6];
  float* out = (float*)d_out;

  char* ws = (char*)d_ws;
  size_t off = 0;
  auto alloc = [&](size_t bytes) {
    void* p = ws + off;
    off += (bytes + 255) & ~(size_t)255;
    return p;
  };
  u16* xb   = (u16*)alloc((size_t)18464 * 768 * 2);   // reused as xa after GEMM0
  u16* WT   = (u16*)alloc((size_t)2304 * 768 * 2);
  u16* WoT  = (u16*)alloc((size_t)768 * 768 * 2);
  u16* qa   = (u16*)alloc((size_t)384 * 577 * 64 * 2);
  u16* ka   = (u16*)alloc((size_t)384 * 577 * 64 * 2);
  u16* vT   = (u16*)alloc((size_t)384 * 64 * 608 * 2);
  u16* biasPk = (u16*)alloc((size_t)76 * 577 * 8 * 2);
  float* b576 = (float*)alloc((size_t)577 * 4);
  (void)ws_size; (void)in_sizes; (void)n_in; (void)out_size;

  cvt_x_kernel<<<(18464 * 768 / 4 + 255) / 256, 256, 0, stream>>>(x, xb, 18464 * 768 / 4);
  dim3 tg(12, 12);
  cvt_wT_kernel<<<tg, 256, 0, stream>>>(Wq, WT);
  cvt_wT_kernel<<<tg, 256, 0, stream>>>(Wk, WT + (size_t)768 * 768);
  cvt_wT_kernel<<<tg, 256, 0, stream>>>(Wv, WT + (size_t)2 * 768 * 768);
  cvt_wT_kernel<<<tg, 256, 0, stream>>>(Wo, WoT);
  bias_kernel<<<(577 * 76 + 255) / 256, 256, 0, stream>>>(bt, biasPk);
  bias576_kernel<<<3, 256, 0, stream>>>(bt, b576);

  // QKV projection: [18464][768] x [768][2304]; 256x256 tiles -> 73 x 9 blocks
  gemm_kernel<0><<<73 * 9, 512, 0, stream>>>(xb, WT, 18464, 9,
                                             nullptr, nullptr, qa, ka, vT);
  // attention -> xa (reuse xb region)
  attn_kernel<<<1920, 256, 0, stream>>>(qa, ka, vT, biasPk, b576, xb);
  // output projection: xa x WoT + bo -> out (f32); 73 x 3 blocks
  gemm_kernel<1><<<73 * 3, 512, 0, stream>>>(xb, WoT, 18464, 3,
                                             out, bo, nullptr, nullptr, nullptr);
}